// Round 1
// baseline (3583.611 us; speedup 1.0000x reference)
//
#include <hip/hip_runtime.h>
#include <hip/hip_bf16.h>

#define BATCH 4
#define SEQ   8192
#define CH    512
#define NHEAD 8
#define HDIM  64
#define KTOK  256
#define FOURC 2048
#define MTOT  (BATCH*SEQ)

__device__ __forceinline__ void expand8(uint4 u, float* f) {
  f[0] = __uint_as_float(u.x << 16); f[1] = __uint_as_float(u.x & 0xffff0000u);
  f[2] = __uint_as_float(u.y << 16); f[3] = __uint_as_float(u.y & 0xffff0000u);
  f[4] = __uint_as_float(u.z << 16); f[5] = __uint_as_float(u.z & 0xffff0000u);
  f[6] = __uint_as_float(u.w << 16); f[7] = __uint_as_float(u.w & 0xffff0000u);
}

// K1: qkvv[m, 2048] = x[m, 512] @ W[512, 2048], output bf16. 64x64 tile, fp32.
__global__ __launch_bounds__(256) void k_gemm_qkvv(
    const float* __restrict__ X, const float* __restrict__ W,
    __hip_bfloat16* __restrict__ QKVV) {
  __shared__ float Xs[32][64];   // [k][m]
  __shared__ float Ws[32][64];   // [k][n]
  const int bn = blockIdx.x * 64;
  const int bm = blockIdx.y * 64;
  const int t = threadIdx.x;
  const int tr = t >> 4, tc = t & 15;
  float acc[4][4] = {};
  for (int k0 = 0; k0 < CH; k0 += 32) {
    int idx = t;
#pragma unroll
    for (int it = 0; it < 2; ++it, idx += 256) {
      int row = idx >> 3;
      int cq  = (idx & 7) << 2;
      float4 v = *reinterpret_cast<const float4*>(&X[(size_t)(bm + row) * CH + k0 + cq]);
      Xs[cq + 0][row] = v.x; Xs[cq + 1][row] = v.y;
      Xs[cq + 2][row] = v.z; Xs[cq + 3][row] = v.w;
    }
    idx = t;
#pragma unroll
    for (int it = 0; it < 2; ++it, idx += 256) {
      int row = idx >> 4;
      int cq  = (idx & 15) << 2;
      *reinterpret_cast<float4*>(&Ws[row][cq]) =
          *reinterpret_cast<const float4*>(&W[(size_t)(k0 + row) * FOURC + bn + cq]);
    }
    __syncthreads();
#pragma unroll
    for (int k = 0; k < 32; ++k) {
      float a[4], b[4];
#pragma unroll
      for (int i = 0; i < 4; ++i) a[i] = Xs[k][tr * 4 + i];
#pragma unroll
      for (int j = 0; j < 4; ++j) b[j] = Ws[k][tc * 4 + j];
#pragma unroll
      for (int i = 0; i < 4; ++i)
#pragma unroll
        for (int j = 0; j < 4; ++j)
          acc[i][j] = fmaf(a[i], b[j], acc[i][j]);
    }
    __syncthreads();
  }
#pragma unroll
  for (int i = 0; i < 4; ++i) {
    size_t m = (size_t)(bm + tr * 4 + i);
    __hip_bfloat16 tmp[4];
#pragma unroll
    for (int j = 0; j < 4; ++j) tmp[j] = __float2bfloat16(acc[i][j]);
    *reinterpret_cast<ushort4*>(&QKVV[m * FOURC + bn + tc * 4]) =
        *reinterpret_cast<ushort4*>(tmp);
  }
}

// K2: inv-norms over tokens: invq/invk[bh*64+d] = 1/sqrt(max(sum_n v^2, eps))
__global__ __launch_bounds__(256) void k_norms(
    const __hip_bfloat16* __restrict__ QKVV,
    float* __restrict__ invq, float* __restrict__ invk) {
  const int bh = blockIdx.x, b = bh >> 3, h = bh & 7;
  const int t = threadIdx.x, d = t & 63, sl = t >> 6;
  __shared__ float red[4][64];
#pragma unroll
  for (int comp = 0; comp < 2; ++comp) {
    const __hip_bfloat16* p = QKVV + (size_t)b * SEQ * FOURC + comp * CH + h * HDIM + d;
    float s = 0.f;
    for (int n = sl; n < SEQ; n += 4) {
      float v = __bfloat162float(p[(size_t)n * FOURC]);
      s = fmaf(v, v, s);
    }
    red[sl][d] = s;
    __syncthreads();
    if (sl == 0) {
      float tot = red[0][d] + red[1][d] + red[2][d] + red[3][d];
      tot = fmaxf(tot, 1e-6f);
      (comp == 0 ? invq : invk)[bh * 64 + d] = 1.0f / sqrtf(tot);
    }
    __syncthreads();
  }
}

// K3: gram G[bh][d][e] += sum_n q[n,d]*k[n,e] (partial per n-slab, atomics)
__global__ __launch_bounds__(256) void k_gram(
    const __hip_bfloat16* __restrict__ QKVV, float* __restrict__ G) {
  const int bh = blockIdx.x, b = bh >> 3, h = bh & 7;
  const int n0 = blockIdx.y * 1024;
  const int t = threadIdx.x, tr = t >> 4, tc = t & 15;
  __shared__ float qs[32][64];
  __shared__ float ks[32][64];
  float acc[4][4] = {};
  const int row = t >> 3, cq = (t & 7) * 8;
  for (int nt = 0; nt < 1024; nt += 32) {
    size_t gb = ((size_t)(b * SEQ + n0 + nt + row)) * FOURC + h * HDIM + cq;
    uint4 uq = *reinterpret_cast<const uint4*>(&QKVV[gb]);
    uint4 uk = *reinterpret_cast<const uint4*>(&QKVV[gb + CH]);
    float fq[8], fk[8];
    expand8(uq, fq); expand8(uk, fk);
#pragma unroll
    for (int j = 0; j < 8; ++j) { qs[row][cq + j] = fq[j]; ks[row][cq + j] = fk[j]; }
    __syncthreads();
#pragma unroll
    for (int n = 0; n < 32; ++n) {
      float a[4], bb[4];
#pragma unroll
      for (int i = 0; i < 4; ++i) a[i] = qs[n][tr * 4 + i];
#pragma unroll
      for (int j = 0; j < 4; ++j) bb[j] = ks[n][tc * 4 + j];
#pragma unroll
      for (int i = 0; i < 4; ++i)
#pragma unroll
        for (int j = 0; j < 4; ++j)
          acc[i][j] = fmaf(a[i], bb[j], acc[i][j]);
    }
    __syncthreads();
  }
  float* gp = G + (size_t)bh * 4096;
#pragma unroll
  for (int i = 0; i < 4; ++i)
#pragma unroll
    for (int j = 0; j < 4; ++j)
      atomicAdd(&gp[(tr * 4 + i) * 64 + tc * 4 + j], acc[i][j]);
}

// K4: attn_ca = softmax_e(G[d][e]*invq[d]*invk[e]*temp_ca[h]) in-place
__global__ __launch_bounds__(64) void k_ca_softmax(
    float* __restrict__ G, const float* __restrict__ invq,
    const float* __restrict__ invk, const float* __restrict__ tca) {
  const int bh = blockIdx.x, h = bh & 7;
  const int d = threadIdx.x;
  float* row = G + (size_t)bh * 4096 + d * 64;
  const float s0 = invq[bh * 64 + d] * tca[h];
  float vals[64];
  float m = -3.0e38f;
#pragma unroll
  for (int e = 0; e < 64; ++e) {
    float v = row[e] * s0 * invk[bh * 64 + e];
    vals[e] = v;
    m = fmaxf(m, v);
  }
  float s = 0.f;
#pragma unroll
  for (int e = 0; e < 64; ++e) { vals[e] = __expf(vals[e] - m); s += vals[e]; }
  float r = 1.0f / s;
#pragma unroll
  for (int e = 0; e < 64; ++e) row[e] = vals[e] * r;
}

// K5: out[b,n,h*64+d] = sum_e attn_ca[bh][d][e] * v_ca[b,n,h*64+e]
__global__ __launch_bounds__(256) void k_xca(
    const __hip_bfloat16* __restrict__ QKVV, const float* __restrict__ A,
    float* __restrict__ out) {
  const int bh = blockIdx.y, b = bh >> 3, h = bh & 7;
  const int n0 = blockIdx.x * 64;
  const int t = threadIdx.x;
  __shared__ float As[64][65];
  __shared__ float vs[16][64];
  for (int i = t; i < 4096; i += 256) As[i >> 6][i & 63] = A[(size_t)bh * 4096 + i];
  __syncthreads();
  const int wave = t >> 6, lane = t & 63;
  const int lrow = t >> 4, lcq = (t & 15) * 4;
  for (int nt = 0; nt < 64; nt += 16) {
    {
      size_t gb = ((size_t)(b * SEQ + n0 + nt + lrow)) * FOURC + 2 * CH + h * HDIM + lcq;
      uint2 u = *reinterpret_cast<const uint2*>(&QKVV[gb]);
      vs[lrow][lcq + 0] = __uint_as_float(u.x << 16);
      vs[lrow][lcq + 1] = __uint_as_float(u.x & 0xffff0000u);
      vs[lrow][lcq + 2] = __uint_as_float(u.y << 16);
      vs[lrow][lcq + 3] = __uint_as_float(u.y & 0xffff0000u);
    }
    __syncthreads();
#pragma unroll
    for (int r = wave; r < 16; r += 4) {
      float acc = 0.f;
#pragma unroll
      for (int e = 0; e < 64; ++e) acc = fmaf(As[lane][e], vs[r][e], acc);
      out[((size_t)(b * SEQ + n0 + nt + r)) * CH + h * HDIM + lane] = acc;
    }
    __syncthreads();
  }
}

// K6: kproj_raw[bh][d][k] = sum_n k[n,d]*P[n,k];  vproj[bh][k][d] = sum_n v_sa[n,d]*P[n,k]
__global__ __launch_bounds__(256) void k_proj(
    const __hip_bfloat16* __restrict__ QKVV, const float* __restrict__ P,
    float* __restrict__ kproj, float* __restrict__ vproj) {
  const int bh = blockIdx.x, b = bh >> 3, h = bh & 7;
  const int k0 = blockIdx.y * 64;
  const int comp = blockIdx.z;                  // 0 -> k, 1 -> v_sa
  const int coff = (comp == 0) ? CH : 3 * CH;
  const int t = threadIdx.x, tr = t >> 4, tc = t & 15;
  __shared__ float as_[32][64];
  __shared__ float ps[32][64];
  float acc[4][4] = {};
  const int arow = t >> 3, acq = (t & 7) * 8;
  for (int nt = 0; nt < SEQ; nt += 32) {
    uint4 u = *reinterpret_cast<const uint4*>(
        &QKVV[((size_t)(b * SEQ + nt + arow)) * FOURC + coff + h * HDIM + acq]);
    float f[8]; expand8(u, f);
#pragma unroll
    for (int j = 0; j < 8; ++j) as_[arow][acq + j] = f[j];
    int idx = t;
#pragma unroll
    for (int it = 0; it < 2; ++it, idx += 256) {
      int row = idx >> 4, cq = (idx & 15) * 4;
      *reinterpret_cast<float4*>(&ps[row][cq]) =
          *reinterpret_cast<const float4*>(&P[(size_t)(nt + row) * KTOK + k0 + cq]);
    }
    __syncthreads();
#pragma unroll
    for (int n = 0; n < 32; ++n) {
      float a[4], bb[4];
#pragma unroll
      for (int i = 0; i < 4; ++i) a[i] = as_[n][tr * 4 + i];
#pragma unroll
      for (int j = 0; j < 4; ++j) bb[j] = ps[n][tc * 4 + j];
#pragma unroll
      for (int i = 0; i < 4; ++i)
#pragma unroll
        for (int j = 0; j < 4; ++j)
          acc[i][j] = fmaf(a[i], bb[j], acc[i][j]);
    }
    __syncthreads();
  }
  if (comp == 0) {
#pragma unroll
    for (int i = 0; i < 4; ++i)
#pragma unroll
      for (int j = 0; j < 4; ++j)
        kproj[((size_t)bh * 64 + tr * 4 + i) * KTOK + k0 + tc * 4 + j] = acc[i][j];
  } else {
#pragma unroll
    for (int i = 0; i < 4; ++i)
#pragma unroll
      for (int j = 0; j < 4; ++j)
        vproj[((size_t)bh * KTOK + k0 + tc * 4 + j) * HDIM + tr * 4 + i] = acc[i][j];
  }
}

// K7: spatial attention fused per row; out += x_sa
__global__ __launch_bounds__(256) void k_xsa(
    const __hip_bfloat16* __restrict__ QKVV,
    const float* __restrict__ kproj, const float* __restrict__ vproj,
    const float* __restrict__ invq, const float* __restrict__ invk,
    const float* __restrict__ tsa, float* __restrict__ out) {
  __shared__ float kp[64][256];   // scaled k_proj
  __shared__ float vp[256][64];   // v_proj transposed
  __shared__ float qb[4][2][64];
  __shared__ float pb[4][2][256];
  const int bh = blockIdx.y, b = bh >> 3, h = bh & 7;
  const int t = threadIdx.x, wave = t >> 6, lane = t & 63;
  for (int i = t; i < 16384; i += 256) {
    int d = i >> 8;
    kp[d][i & 255] = kproj[(size_t)bh * 16384 + i] * invk[bh * 64 + d];
  }
  for (int i = t; i < 16384; i += 256)
    vp[i >> 6][i & 63] = vproj[(size_t)bh * 16384 + i];
  __syncthreads();
  const float qscale = invq[bh * 64 + lane] * tsa[h];
  const int n0 = blockIdx.x * 512;
  const __hip_bfloat16* qbase = QKVV + (size_t)b * SEQ * FOURC + h * HDIM + lane;
  for (int pr = wave * 2; pr < 512; pr += 8) {
    const int n = n0 + pr;
    float q0 = __bfloat162float(qbase[(size_t)n * FOURC]) * qscale;
    float q1 = __bfloat162float(qbase[(size_t)(n + 1) * FOURC]) * qscale;
    qb[wave][0][lane] = q0;
    qb[wave][1][lane] = q1;
    __builtin_amdgcn_wave_barrier();
    float s0[4] = {0, 0, 0, 0}, s1[4] = {0, 0, 0, 0};
#pragma unroll 8
    for (int d = 0; d < 64; ++d) {
      float a0 = qb[wave][0][d], a1 = qb[wave][1][d];
#pragma unroll
      for (int j = 0; j < 4; ++j) {
        float kv = kp[d][j * 64 + lane];
        s0[j] = fmaf(a0, kv, s0[j]);
        s1[j] = fmaf(a1, kv, s1[j]);
      }
    }
    float m0 = fmaxf(fmaxf(s0[0], s0[1]), fmaxf(s0[2], s0[3]));
    float m1 = fmaxf(fmaxf(s1[0], s1[1]), fmaxf(s1[2], s1[3]));
#pragma unroll
    for (int off = 32; off > 0; off >>= 1) {
      m0 = fmaxf(m0, __shfl_xor(m0, off));
      m1 = fmaxf(m1, __shfl_xor(m1, off));
    }
    float e0[4], e1[4], sum0 = 0.f, sum1 = 0.f;
#pragma unroll
    for (int j = 0; j < 4; ++j) {
      e0[j] = __expf(s0[j] - m0); sum0 += e0[j];
      e1[j] = __expf(s1[j] - m1); sum1 += e1[j];
    }
#pragma unroll
    for (int off = 32; off > 0; off >>= 1) {
      sum0 += __shfl_xor(sum0, off);
      sum1 += __shfl_xor(sum1, off);
    }
    float r0 = 1.0f / sum0, r1 = 1.0f / sum1;
#pragma unroll
    for (int j = 0; j < 4; ++j) {
      pb[wave][0][j * 64 + lane] = e0[j] * r0;
      pb[wave][1][j * 64 + lane] = e1[j] * r1;
    }
    __builtin_amdgcn_wave_barrier();
    float acc0 = 0.f, acc1 = 0.f;
#pragma unroll 16
    for (int k = 0; k < 256; ++k) {
      float vv = vp[k][lane];
      acc0 = fmaf(pb[wave][0][k], vv, acc0);
      acc1 = fmaf(pb[wave][1][k], vv, acc1);
    }
    size_t o = ((size_t)(b * SEQ + n)) * CH + h * HDIM + lane;
    out[o] += acc0;
    out[o + CH] += acc1;
  }
}

extern "C" void kernel_launch(void* const* d_in, const int* in_sizes, int n_in,
                              void* d_out, int out_size, void* d_ws, size_t ws_size,
                              hipStream_t stream) {
  const float* x   = (const float*)d_in[0];
  const float* w   = (const float*)d_in[1];
  const float* sp  = (const float*)d_in[2];
  const float* tca = (const float*)d_in[3];
  const float* tsa = (const float*)d_in[4];
  float* out = (float*)d_out;
  char* ws = (char*)d_ws;

  __hip_bfloat16* qkvv = (__hip_bfloat16*)ws;                 // 134217728 B
  float* G     = (float*)(ws + 134217728);                    // 524288 B
  float* invq  = (float*)(ws + 134742016);                    // 8192 B
  float* invk  = (float*)(ws + 134750208);                    // 8192 B
  float* kproj = (float*)(ws + 134758400);                    // 2097152 B
  float* vproj = (float*)(ws + 136855552);                    // 2097152 B

  hipLaunchKernelGGL(k_gemm_qkvv, dim3(32, 512), dim3(256), 0, stream, x, w, qkvv);
  hipMemsetAsync(G, 0, 32 * 64 * 64 * sizeof(float), stream);
  hipLaunchKernelGGL(k_norms, dim3(32), dim3(256), 0, stream, qkvv, invq, invk);
  hipLaunchKernelGGL(k_gram, dim3(32, 8), dim3(256), 0, stream, qkvv, G);
  hipLaunchKernelGGL(k_ca_softmax, dim3(32), dim3(64), 0, stream, G, invq, invk, tca);
  hipLaunchKernelGGL(k_xca, dim3(128, 32), dim3(256), 0, stream, qkvv, G, out);
  hipLaunchKernelGGL(k_proj, dim3(32, 4, 2), dim3(256), 0, stream, qkvv, sp, kproj, vproj);
  hipLaunchKernelGGL(k_xsa, dim3(16, 32), dim3(256), 0, stream, qkvv, kproj, vproj,
                     invq, invk, tsa, out);
}

// Round 2
// 1548.636 us; speedup vs baseline: 2.3140x; 2.3140x over previous
//
#include <hip/hip_runtime.h>
#include <hip/hip_bf16.h>

#define BATCH 4
#define SEQ   8192
#define CH    512
#define NHEAD 8
#define HDIM  64
#define KTOK  256
#define FOURC 2048
#define MTOT  (BATCH*SEQ)

typedef __attribute__((ext_vector_type(8))) short bf16x8;
typedef __attribute__((ext_vector_type(4))) float f32x4;

__device__ __forceinline__ void expand8(uint4 u, float* f) {
  f[0] = __uint_as_float(u.x << 16); f[1] = __uint_as_float(u.x & 0xffff0000u);
  f[2] = __uint_as_float(u.y << 16); f[3] = __uint_as_float(u.y & 0xffff0000u);
  f[4] = __uint_as_float(u.z << 16); f[5] = __uint_as_float(u.z & 0xffff0000u);
  f[6] = __uint_as_float(u.w << 16); f[7] = __uint_as_float(u.w & 0xffff0000u);
}

// K0: W [512][2048] fp32 -> Wt [2048][512] bf16 (transpose + convert)
__global__ __launch_bounds__(256) void k_wt(
    const float* __restrict__ W, __hip_bfloat16* __restrict__ Wt) {
  __shared__ float tile[32][33];
  const int bx = blockIdx.x * 32;   // n
  const int by = blockIdx.y * 32;   // k
  const int t = threadIdx.x;
  const int r = t >> 5, c = t & 31;
#pragma unroll
  for (int it = 0; it < 4; ++it)
    tile[r + it * 8][c] = W[(size_t)(by + r + it * 8) * FOURC + bx + c];
  __syncthreads();
#pragma unroll
  for (int it = 0; it < 4; ++it) {
    int n = r + it * 8;
    Wt[(size_t)(bx + n) * CH + by + c] = __float2bfloat16(tile[c][n]);
  }
}

// K1: qkvv[m, 2048] = x[m, 512] @ W[512, 2048] via bf16 MFMA, out bf16.
// 128x128 tile, BK=32, 4 waves (2x2), each wave 64x64 = 4x4 fragments.
__global__ __launch_bounds__(256) void k_gemm_mfma(
    const float* __restrict__ X, const __hip_bfloat16* __restrict__ Wt,
    __hip_bfloat16* __restrict__ QKVV) {
  __shared__ __align__(16) __hip_bfloat16 As[128 * 32];  // [m][k]
  __shared__ __align__(16) __hip_bfloat16 Bs[128 * 32];  // [n][k] (B^T)
  const int t = threadIdx.x;
  const int wid = t >> 6, lane = t & 63;
  const int bn = blockIdx.x * 128;
  const int bm = blockIdx.y * 128;
  const int wr = wid >> 1, wc = wid & 1;
  const int lrow = lane & 15, lk = (lane >> 4) * 8;
  f32x4 acc[4][4] = {};
  for (int k0 = 0; k0 < CH; k0 += 32) {
    // stage A: convert fp32 -> bf16 in-register
#pragma unroll
    for (int it = 0; it < 4; ++it) {
      int e = (it * 256 + t) * 4;
      int m = e >> 5, k = e & 31;
      float4 v = *reinterpret_cast<const float4*>(&X[(size_t)(bm + m) * CH + k0 + k]);
      __hip_bfloat16 tmp[4];
      tmp[0] = __float2bfloat16(v.x); tmp[1] = __float2bfloat16(v.y);
      tmp[2] = __float2bfloat16(v.z); tmp[3] = __float2bfloat16(v.w);
      *reinterpret_cast<uint2*>(&As[e]) = *reinterpret_cast<const uint2*>(tmp);
    }
    // stage B: bf16x8 copy
#pragma unroll
    for (int it = 0; it < 2; ++it) {
      int fe = (it * 256 + t) * 8;
      int n = fe >> 5, k = fe & 31;
      *reinterpret_cast<uint4*>(&Bs[fe]) =
          *reinterpret_cast<const uint4*>(&Wt[(size_t)(bn + n) * CH + k0 + k]);
    }
    __syncthreads();
    bf16x8 af[4], bfr[4];
#pragma unroll
    for (int i = 0; i < 4; ++i)
      af[i] = *reinterpret_cast<const bf16x8*>(&As[(wr * 64 + i * 16 + lrow) * 32 + lk]);
#pragma unroll
    for (int j = 0; j < 4; ++j)
      bfr[j] = *reinterpret_cast<const bf16x8*>(&Bs[(wc * 64 + j * 16 + lrow) * 32 + lk]);
#pragma unroll
    for (int i = 0; i < 4; ++i)
#pragma unroll
      for (int j = 0; j < 4; ++j)
        acc[i][j] = __builtin_amdgcn_mfma_f32_16x16x32_bf16(af[i], bfr[j], acc[i][j], 0, 0, 0);
    __syncthreads();
  }
  const int l4 = (lane >> 4) * 4;
#pragma unroll
  for (int i = 0; i < 4; ++i)
#pragma unroll
    for (int j = 0; j < 4; ++j) {
      int col = bn + wc * 64 + j * 16 + lrow;
#pragma unroll
      for (int r = 0; r < 4; ++r) {
        int row = bm + wr * 64 + i * 16 + l4 + r;
        QKVV[(size_t)row * FOURC + col] = __float2bfloat16(acc[i][j][r]);
      }
    }
}

// K2: coalesced sum-of-squares over tokens -> sumsq[comp][bh][d] (atomic partials)
__global__ __launch_bounds__(256) void k_norms2(
    const __hip_bfloat16* __restrict__ QKVV, float* __restrict__ sumsq) {
  const int bh = blockIdx.y, b = bh >> 3, h = bh & 7;
  const int n0 = blockIdx.x * 256;
  const int t = threadIdx.x;
  const int rt = t >> 3, cg = t & 7;
  __shared__ float red[32][64];
#pragma unroll
  for (int comp = 0; comp < 2; ++comp) {
    float s[8] = {};
    const size_t base = (size_t)(b * SEQ + n0) * FOURC + comp * CH + h * HDIM + cg * 8;
    for (int r = rt; r < 256; r += 32) {
      uint4 u = *reinterpret_cast<const uint4*>(&QKVV[base + (size_t)r * FOURC]);
      float f[8]; expand8(u, f);
#pragma unroll
      for (int j = 0; j < 8; ++j) s[j] = fmaf(f[j], f[j], s[j]);
    }
#pragma unroll
    for (int j = 0; j < 8; ++j) red[rt][cg * 8 + j] = s[j];
    __syncthreads();
    if (t < 64) {
      float tot = 0.f;
#pragma unroll
      for (int r = 0; r < 32; ++r) tot += red[r][t];
      atomicAdd(&sumsq[comp * 2048 + bh * 64 + t], tot);
    }
    __syncthreads();
  }
}

// K2b: invq/invk = rsqrt(max(sumsq, eps))
__global__ __launch_bounds__(256) void k_finalize(
    const float* __restrict__ sumsq, float* __restrict__ invq, float* __restrict__ invk) {
  int i = blockIdx.x * 256 + threadIdx.x;
  if (i < 2048) {
    invq[i] = rsqrtf(fmaxf(sumsq[i], 1e-6f));
    invk[i] = rsqrtf(fmaxf(sumsq[2048 + i], 1e-6f));
  }
}

// K3: gram G[bh][d][e] += sum_n q[n,d]*k[n,e] (partial per n-slab, atomics)
__global__ __launch_bounds__(256) void k_gram(
    const __hip_bfloat16* __restrict__ QKVV, float* __restrict__ G) {
  const int bh = blockIdx.x, b = bh >> 3, h = bh & 7;
  const int n0 = blockIdx.y * 1024;
  const int t = threadIdx.x, tr = t >> 4, tc = t & 15;
  __shared__ float qs[32][64];
  __shared__ float ks[32][64];
  float acc[4][4] = {};
  const int row = t >> 3, cq = (t & 7) * 8;
  for (int nt = 0; nt < 1024; nt += 32) {
    size_t gb = ((size_t)(b * SEQ + n0 + nt + row)) * FOURC + h * HDIM + cq;
    uint4 uq = *reinterpret_cast<const uint4*>(&QKVV[gb]);
    uint4 uk = *reinterpret_cast<const uint4*>(&QKVV[gb + CH]);
    float fq[8], fk[8];
    expand8(uq, fq); expand8(uk, fk);
#pragma unroll
    for (int j = 0; j < 8; ++j) { qs[row][cq + j] = fq[j]; ks[row][cq + j] = fk[j]; }
    __syncthreads();
#pragma unroll
    for (int n = 0; n < 32; ++n) {
      float a[4], bb[4];
#pragma unroll
      for (int i = 0; i < 4; ++i) a[i] = qs[n][tr * 4 + i];
#pragma unroll
      for (int j = 0; j < 4; ++j) bb[j] = ks[n][tc * 4 + j];
#pragma unroll
      for (int i = 0; i < 4; ++i)
#pragma unroll
        for (int j = 0; j < 4; ++j)
          acc[i][j] = fmaf(a[i], bb[j], acc[i][j]);
    }
    __syncthreads();
  }
  float* gp = G + (size_t)bh * 4096;
#pragma unroll
  for (int i = 0; i < 4; ++i)
#pragma unroll
    for (int j = 0; j < 4; ++j)
      atomicAdd(&gp[(tr * 4 + i) * 64 + tc * 4 + j], acc[i][j]);
}

// K4: attn_ca = softmax_e(G[d][e]*invq[d]*invk[e]*temp_ca[h]) in-place
__global__ __launch_bounds__(64) void k_ca_softmax(
    float* __restrict__ G, const float* __restrict__ invq,
    const float* __restrict__ invk, const float* __restrict__ tca) {
  const int bh = blockIdx.x, h = bh & 7;
  const int d = threadIdx.x;
  float* row = G + (size_t)bh * 4096 + d * 64;
  const float s0 = invq[bh * 64 + d] * tca[h];
  float vals[64];
  float m = -3.0e38f;
#pragma unroll
  for (int e = 0; e < 64; ++e) {
    float v = row[e] * s0 * invk[bh * 64 + e];
    vals[e] = v;
    m = fmaxf(m, v);
  }
  float s = 0.f;
#pragma unroll
  for (int e = 0; e < 64; ++e) { vals[e] = __expf(vals[e] - m); s += vals[e]; }
  float r = 1.0f / s;
#pragma unroll
  for (int e = 0; e < 64; ++e) row[e] = vals[e] * r;
}

// K5: out[b,n,h*64+d] = sum_e attn_ca[bh][d][e] * v_ca[b,n,h*64+e]
__global__ __launch_bounds__(256) void k_xca(
    const __hip_bfloat16* __restrict__ QKVV, const float* __restrict__ A,
    float* __restrict__ out) {
  const int bh = blockIdx.y, b = bh >> 3, h = bh & 7;
  const int n0 = blockIdx.x * 64;
  const int t = threadIdx.x;
  __shared__ float As[64][65];
  __shared__ float vs[16][64];
  for (int i = t; i < 4096; i += 256) As[i >> 6][i & 63] = A[(size_t)bh * 4096 + i];
  __syncthreads();
  const int wave = t >> 6, lane = t & 63;
  const int lrow = t >> 4, lcq = (t & 15) * 4;
  for (int nt = 0; nt < 64; nt += 16) {
    {
      size_t gb = ((size_t)(b * SEQ + n0 + nt + lrow)) * FOURC + 2 * CH + h * HDIM + lcq;
      uint2 u = *reinterpret_cast<const uint2*>(&QKVV[gb]);
      vs[lrow][lcq + 0] = __uint_as_float(u.x << 16);
      vs[lrow][lcq + 1] = __uint_as_float(u.x & 0xffff0000u);
      vs[lrow][lcq + 2] = __uint_as_float(u.y << 16);
      vs[lrow][lcq + 3] = __uint_as_float(u.y & 0xffff0000u);
    }
    __syncthreads();
#pragma unroll
    for (int r = wave; r < 16; r += 4) {
      float acc = 0.f;
#pragma unroll
      for (int e = 0; e < 64; ++e) acc = fmaf(As[lane][e], vs[r][e], acc);
      out[((size_t)(b * SEQ + n0 + nt + r)) * CH + h * HDIM + lane] = acc;
    }
    __syncthreads();
  }
}

// K6: kproj[bh][d][k] = sum_n k[n,d]*P[n,k];  vproj[bh][k][d] = sum_n v_sa[n,d]*P[n,k]
__global__ __launch_bounds__(256) void k_proj(
    const __hip_bfloat16* __restrict__ QKVV, const float* __restrict__ P,
    float* __restrict__ kproj, float* __restrict__ vproj) {
  const int bh = blockIdx.x, b = bh >> 3, h = bh & 7;
  const int k0 = blockIdx.y * 64;
  const int comp = blockIdx.z;
  const int coff = (comp == 0) ? CH : 3 * CH;
  const int t = threadIdx.x, tr = t >> 4, tc = t & 15;
  __shared__ float as_[32][64];
  __shared__ float ps[32][64];
  float acc[4][4] = {};
  const int arow = t >> 3, acq = (t & 7) * 8;
  for (int nt = 0; nt < SEQ; nt += 32) {
    uint4 u = *reinterpret_cast<const uint4*>(
        &QKVV[((size_t)(b * SEQ + nt + arow)) * FOURC + coff + h * HDIM + acq]);
    float f[8]; expand8(u, f);
#pragma unroll
    for (int j = 0; j < 8; ++j) as_[arow][acq + j] = f[j];
    int idx = t;
#pragma unroll
    for (int it = 0; it < 2; ++it, idx += 256) {
      int row = idx >> 4, cq = (idx & 15) * 4;
      *reinterpret_cast<float4*>(&ps[row][cq]) =
          *reinterpret_cast<const float4*>(&P[(size_t)(nt + row) * KTOK + k0 + cq]);
    }
    __syncthreads();
#pragma unroll
    for (int n = 0; n < 32; ++n) {
      float a[4], bb[4];
#pragma unroll
      for (int i = 0; i < 4; ++i) a[i] = as_[n][tr * 4 + i];
#pragma unroll
      for (int j = 0; j < 4; ++j) bb[j] = ps[n][tc * 4 + j];
#pragma unroll
      for (int i = 0; i < 4; ++i)
#pragma unroll
        for (int j = 0; j < 4; ++j)
          acc[i][j] = fmaf(a[i], bb[j], acc[i][j]);
    }
    __syncthreads();
  }
  if (comp == 0) {
#pragma unroll
    for (int i = 0; i < 4; ++i)
#pragma unroll
      for (int j = 0; j < 4; ++j)
        kproj[((size_t)bh * 64 + tr * 4 + i) * KTOK + k0 + tc * 4 + j] = acc[i][j];
  } else {
#pragma unroll
    for (int i = 0; i < 4; ++i)
#pragma unroll
      for (int j = 0; j < 4; ++j)
        vproj[((size_t)bh * KTOK + k0 + tc * 4 + j) * HDIM + tr * 4 + i] = acc[i][j];
  }
}

// K7: spatial attention fused per row; out += x_sa
__global__ __launch_bounds__(256) void k_xsa(
    const __hip_bfloat16* __restrict__ QKVV,
    const float* __restrict__ kproj, const float* __restrict__ vproj,
    const float* __restrict__ invq, const float* __restrict__ invk,
    const float* __restrict__ tsa, float* __restrict__ out) {
  __shared__ float kp[64][256];
  __shared__ float vp[256][64];
  __shared__ float qb[4][2][64];
  __shared__ float pb[4][2][256];
  const int bh = blockIdx.y, b = bh >> 3, h = bh & 7;
  const int t = threadIdx.x, wave = t >> 6, lane = t & 63;
  for (int i = t; i < 16384; i += 256) {
    int d = i >> 8;
    kp[d][i & 255] = kproj[(size_t)bh * 16384 + i] * invk[bh * 64 + d];
  }
  for (int i = t; i < 16384; i += 256)
    vp[i >> 6][i & 63] = vproj[(size_t)bh * 16384 + i];
  __syncthreads();
  const float qscale = invq[bh * 64 + lane] * tsa[h];
  const int n0 = blockIdx.x * 512;
  const __hip_bfloat16* qbase = QKVV + (size_t)b * SEQ * FOURC + h * HDIM + lane;
  for (int pr = wave * 2; pr < 512; pr += 8) {
    const int n = n0 + pr;
    float q0 = __bfloat162float(qbase[(size_t)n * FOURC]) * qscale;
    float q1 = __bfloat162float(qbase[(size_t)(n + 1) * FOURC]) * qscale;
    qb[wave][0][lane] = q0;
    qb[wave][1][lane] = q1;
    __builtin_amdgcn_wave_barrier();
    float s0[4] = {0, 0, 0, 0}, s1[4] = {0, 0, 0, 0};
#pragma unroll 8
    for (int d = 0; d < 64; ++d) {
      float a0 = qb[wave][0][d], a1 = qb[wave][1][d];
#pragma unroll
      for (int j = 0; j < 4; ++j) {
        float kv = kp[d][j * 64 + lane];
        s0[j] = fmaf(a0, kv, s0[j]);
        s1[j] = fmaf(a1, kv, s1[j]);
      }
    }
    float m0 = fmaxf(fmaxf(s0[0], s0[1]), fmaxf(s0[2], s0[3]));
    float m1 = fmaxf(fmaxf(s1[0], s1[1]), fmaxf(s1[2], s1[3]));
#pragma unroll
    for (int off = 32; off > 0; off >>= 1) {
      m0 = fmaxf(m0, __shfl_xor(m0, off));
      m1 = fmaxf(m1, __shfl_xor(m1, off));
    }
    float e0[4], e1[4], sum0 = 0.f, sum1 = 0.f;
#pragma unroll
    for (int j = 0; j < 4; ++j) {
      e0[j] = __expf(s0[j] - m0); sum0 += e0[j];
      e1[j] = __expf(s1[j] - m1); sum1 += e1[j];
    }
#pragma unroll
    for (int off = 32; off > 0; off >>= 1) {
      sum0 += __shfl_xor(sum0, off);
      sum1 += __shfl_xor(sum1, off);
    }
    float r0 = 1.0f / sum0, r1 = 1.0f / sum1;
#pragma unroll
    for (int j = 0; j < 4; ++j) {
      pb[wave][0][j * 64 + lane] = e0[j] * r0;
      pb[wave][1][j * 64 + lane] = e1[j] * r1;
    }
    __builtin_amdgcn_wave_barrier();
    float acc0 = 0.f, acc1 = 0.f;
#pragma unroll 16
    for (int k = 0; k < 256; ++k) {
      float vv = vp[k][lane];
      acc0 = fmaf(pb[wave][0][k], vv, acc0);
      acc1 = fmaf(pb[wave][1][k], vv, acc1);
    }
    size_t o = ((size_t)(b * SEQ + n)) * CH + h * HDIM + lane;
    out[o] += acc0;
    out[o + CH] += acc1;
  }
}

extern "C" void kernel_launch(void* const* d_in, const int* in_sizes, int n_in,
                              void* d_out, int out_size, void* d_ws, size_t ws_size,
                              hipStream_t stream) {
  const float* x   = (const float*)d_in[0];
  const float* w   = (const float*)d_in[1];
  const float* sp  = (const float*)d_in[2];
  const float* tca = (const float*)d_in[3];
  const float* tsa = (const float*)d_in[4];
  float* out = (float*)d_out;
  char* ws = (char*)d_ws;

  __hip_bfloat16* qkvv = (__hip_bfloat16*)ws;                 // 134217728 B
  __hip_bfloat16* wt   = (__hip_bfloat16*)(ws + 134217728);   // 2097152 B
  float* G     = (float*)(ws + 136314880);                    // 524288 B
  float* sumsq = (float*)(ws + 136839168);                    // 16384 B
  float* invq  = (float*)(ws + 136855552);                    // 8192 B
  float* invk  = (float*)(ws + 136863744);                    // 8192 B
  float* kproj = (float*)(ws + 136871936);                    // 2097152 B
  float* vproj = (float*)(ws + 138969088);                    // 2097152 B

  hipMemsetAsync(G, 0, 524288, stream);
  hipMemsetAsync(sumsq, 0, 16384, stream);
  hipLaunchKernelGGL(k_wt, dim3(64, 16), dim3(256), 0, stream, w, wt);
  hipLaunchKernelGGL(k_gemm_mfma, dim3(16, 256), dim3(256), 0, stream, x, wt, qkvv);
  hipLaunchKernelGGL(k_norms2, dim3(32, 32), dim3(256), 0, stream, qkvv, sumsq);
  hipLaunchKernelGGL(k_finalize, dim3(8), dim3(256), 0, stream, sumsq, invq, invk);
  hipLaunchKernelGGL(k_gram, dim3(32, 8), dim3(256), 0, stream, qkvv, G);
  hipLaunchKernelGGL(k_ca_softmax, dim3(32), dim3(64), 0, stream, G, invq, invk, tca);
  hipLaunchKernelGGL(k_xca, dim3(128, 32), dim3(256), 0, stream, qkvv, G, out);
  hipLaunchKernelGGL(k_proj, dim3(32, 4, 2), dim3(256), 0, stream, qkvv, sp, kproj, vproj);
  hipLaunchKernelGGL(k_xsa, dim3(16, 32), dim3(256), 0, stream, qkvv, kproj, vproj,
                     invq, invk, tsa, out);
}

// Round 3
// 423.094 us; speedup vs baseline: 8.4700x; 3.6603x over previous
//
#include <hip/hip_runtime.h>
#include <hip/hip_bf16.h>

#define BATCH 4
#define SEQ   8192
#define CH    512
#define NHEAD 8
#define HDIM  64
#define KTOK  256
#define FOURC 2048

typedef __attribute__((ext_vector_type(8))) short bf16x8;
typedef __attribute__((ext_vector_type(4))) float f32x4;

__device__ __forceinline__ void expand8(uint4 u, float* f) {
  f[0] = __uint_as_float(u.x << 16); f[1] = __uint_as_float(u.x & 0xffff0000u);
  f[2] = __uint_as_float(u.y << 16); f[3] = __uint_as_float(u.y & 0xffff0000u);
  f[4] = __uint_as_float(u.z << 16); f[5] = __uint_as_float(u.z & 0xffff0000u);
  f[6] = __uint_as_float(u.w << 16); f[7] = __uint_as_float(u.w & 0xffff0000u);
}

__device__ __forceinline__ ushort bf16bits(float f) {
  __hip_bfloat16 b = __float2bfloat16(f);
  return *reinterpret_cast<ushort*>(&b);
}
__device__ __forceinline__ uint packbf2(float lo, float hi) {
  return (uint)bf16bits(lo) | ((uint)bf16bits(hi) << 16);
}

// ---------------- K0: W [512][2048] fp32 -> Wt [2048][512] bf16 ----------------
__global__ __launch_bounds__(256) void k_wt(
    const float* __restrict__ W, __hip_bfloat16* __restrict__ Wt) {
  __shared__ float tile[32][33];
  const int bx = blockIdx.x * 32;   // n
  const int by = blockIdx.y * 32;   // k
  const int t = threadIdx.x;
  const int r = t >> 5, c = t & 31;
#pragma unroll
  for (int it = 0; it < 4; ++it)
    tile[r + it * 8][c] = W[(size_t)(by + r + it * 8) * FOURC + bx + c];
  __syncthreads();
#pragma unroll
  for (int it = 0; it < 4; ++it) {
    int n = r + it * 8;
    Wt[(size_t)(bx + n) * CH + by + c] = __float2bfloat16(tile[c][n]);
  }
}

// ---------------- K0b: P [8192][256] fp32 -> Pt [256][8192] bf16 ----------------
__global__ __launch_bounds__(256) void k_pt(
    const float* __restrict__ P, __hip_bfloat16* __restrict__ Pt) {
  __shared__ float tile[32][33];
  const int n0 = blockIdx.x * 32, k0 = blockIdx.y * 32;
  const int t = threadIdx.x, r = t >> 5, c = t & 31;
#pragma unroll
  for (int i = 0; i < 4; ++i)
    tile[r + i * 8][c] = P[(size_t)(n0 + r + i * 8) * KTOK + k0 + c];
  __syncthreads();
#pragma unroll
  for (int i = 0; i < 4; ++i)
    Pt[(size_t)(k0 + r + i * 8) * SEQ + n0 + c] = __float2bfloat16(tile[c][r + i * 8]);
}

// ---------------- K1: qkvv = x @ W via bf16 MFMA ----------------
__global__ __launch_bounds__(256) void k_gemm_mfma(
    const float* __restrict__ X, const __hip_bfloat16* __restrict__ Wt,
    __hip_bfloat16* __restrict__ QKVV) {
  __shared__ __align__(16) __hip_bfloat16 As[128 * 32];
  __shared__ __align__(16) __hip_bfloat16 Bs[128 * 32];
  const int t = threadIdx.x;
  const int wid = t >> 6, lane = t & 63;
  const int bn = blockIdx.x * 128;
  const int bm = blockIdx.y * 128;
  const int wr = wid >> 1, wc = wid & 1;
  const int lrow = lane & 15, lk = (lane >> 4) * 8;
  f32x4 acc[4][4] = {};
  for (int k0 = 0; k0 < CH; k0 += 32) {
#pragma unroll
    for (int it = 0; it < 4; ++it) {
      int e = (it * 256 + t) * 4;
      int m = e >> 5, k = e & 31;
      float4 v = *reinterpret_cast<const float4*>(&X[(size_t)(bm + m) * CH + k0 + k]);
      __hip_bfloat16 tmp[4];
      tmp[0] = __float2bfloat16(v.x); tmp[1] = __float2bfloat16(v.y);
      tmp[2] = __float2bfloat16(v.z); tmp[3] = __float2bfloat16(v.w);
      *reinterpret_cast<uint2*>(&As[e]) = *reinterpret_cast<const uint2*>(tmp);
    }
#pragma unroll
    for (int it = 0; it < 2; ++it) {
      int fe = (it * 256 + t) * 8;
      int n = fe >> 5, k = fe & 31;
      *reinterpret_cast<uint4*>(&Bs[fe]) =
          *reinterpret_cast<const uint4*>(&Wt[(size_t)(bn + n) * CH + k0 + k]);
    }
    __syncthreads();
    bf16x8 af[4], bfr[4];
#pragma unroll
    for (int i = 0; i < 4; ++i)
      af[i] = *reinterpret_cast<const bf16x8*>(&As[(wr * 64 + i * 16 + lrow) * 32 + lk]);
#pragma unroll
    for (int j = 0; j < 4; ++j)
      bfr[j] = *reinterpret_cast<const bf16x8*>(&Bs[(wc * 64 + j * 16 + lrow) * 32 + lk]);
#pragma unroll
    for (int i = 0; i < 4; ++i)
#pragma unroll
      for (int j = 0; j < 4; ++j)
        acc[i][j] = __builtin_amdgcn_mfma_f32_16x16x32_bf16(af[i], bfr[j], acc[i][j], 0, 0, 0);
    __syncthreads();
  }
  const int l4 = (lane >> 4) * 4;
#pragma unroll
  for (int i = 0; i < 4; ++i)
#pragma unroll
    for (int j = 0; j < 4; ++j) {
      int col = bn + wc * 64 + j * 16 + lrow;
#pragma unroll
      for (int r = 0; r < 4; ++r) {
        int row = bm + wr * 64 + i * 16 + l4 + r;
        QKVV[(size_t)row * FOURC + col] = __float2bfloat16(acc[i][j][r]);
      }
    }
}

// ---------------- K2: sum-of-squares over tokens ----------------
__global__ __launch_bounds__(256) void k_norms2(
    const __hip_bfloat16* __restrict__ QKVV, float* __restrict__ sumsq) {
  const int bh = blockIdx.y, b = bh >> 3, h = bh & 7;
  const int n0 = blockIdx.x * 256;
  const int t = threadIdx.x;
  const int rt = t >> 3, cg = t & 7;
  __shared__ float red[32][64];
#pragma unroll
  for (int comp = 0; comp < 2; ++comp) {
    float s[8] = {};
    const size_t base = (size_t)(b * SEQ + n0) * FOURC + comp * CH + h * HDIM + cg * 8;
    for (int r = rt; r < 256; r += 32) {
      uint4 u = *reinterpret_cast<const uint4*>(&QKVV[base + (size_t)r * FOURC]);
      float f[8]; expand8(u, f);
#pragma unroll
      for (int j = 0; j < 8; ++j) s[j] = fmaf(f[j], f[j], s[j]);
    }
#pragma unroll
    for (int j = 0; j < 8; ++j) red[rt][cg * 8 + j] = s[j];
    __syncthreads();
    if (t < 64) {
      float tot = 0.f;
#pragma unroll
      for (int r = 0; r < 32; ++r) tot += red[r][t];
      atomicAdd(&sumsq[comp * 2048 + bh * 64 + t], tot);
    }
    __syncthreads();
  }
}

__global__ __launch_bounds__(256) void k_finalize(
    const float* __restrict__ sumsq, float* __restrict__ invq, float* __restrict__ invk) {
  int i = blockIdx.x * 256 + threadIdx.x;
  if (i < 2048) {
    invq[i] = rsqrtf(fmaxf(sumsq[i], 1e-6f));
    invk[i] = rsqrtf(fmaxf(sumsq[2048 + i], 1e-6f));
  }
}

// ---------------- K3: gram (fp32, unchanged) ----------------
__global__ __launch_bounds__(256) void k_gram(
    const __hip_bfloat16* __restrict__ QKVV, float* __restrict__ G) {
  const int bh = blockIdx.x, b = bh >> 3, h = bh & 7;
  const int n0 = blockIdx.y * 1024;
  const int t = threadIdx.x, tr = t >> 4, tc = t & 15;
  __shared__ float qs[32][64];
  __shared__ float ks[32][64];
  float acc[4][4] = {};
  const int row = t >> 3, cq = (t & 7) * 8;
  for (int nt = 0; nt < 1024; nt += 32) {
    size_t gb = ((size_t)(b * SEQ + n0 + nt + row)) * FOURC + h * HDIM + cq;
    uint4 uq = *reinterpret_cast<const uint4*>(&QKVV[gb]);
    uint4 uk = *reinterpret_cast<const uint4*>(&QKVV[gb + CH]);
    float fq[8], fk[8];
    expand8(uq, fq); expand8(uk, fk);
#pragma unroll
    for (int j = 0; j < 8; ++j) { qs[row][cq + j] = fq[j]; ks[row][cq + j] = fk[j]; }
    __syncthreads();
#pragma unroll
    for (int n = 0; n < 32; ++n) {
      float a[4], bb[4];
#pragma unroll
      for (int i = 0; i < 4; ++i) a[i] = qs[n][tr * 4 + i];
#pragma unroll
      for (int j = 0; j < 4; ++j) bb[j] = ks[n][tc * 4 + j];
#pragma unroll
      for (int i = 0; i < 4; ++i)
#pragma unroll
        for (int j = 0; j < 4; ++j)
          acc[i][j] = fmaf(a[i], bb[j], acc[i][j]);
    }
    __syncthreads();
  }
  float* gp = G + (size_t)bh * 4096;
#pragma unroll
  for (int i = 0; i < 4; ++i)
#pragma unroll
    for (int j = 0; j < 4; ++j)
      atomicAdd(&gp[(tr * 4 + i) * 64 + tc * 4 + j], acc[i][j]);
}

// ---------------- K4: channel-attention softmax (unchanged) ----------------
__global__ __launch_bounds__(64) void k_ca_softmax(
    float* __restrict__ G, const float* __restrict__ invq,
    const float* __restrict__ invk, const float* __restrict__ tca) {
  const int bh = blockIdx.x, h = bh & 7;
  const int d = threadIdx.x;
  float* row = G + (size_t)bh * 4096 + d * 64;
  const float s0 = invq[bh * 64 + d] * tca[h];
  float vals[64];
  float m = -3.0e38f;
#pragma unroll
  for (int e = 0; e < 64; ++e) {
    float v = row[e] * s0 * invk[bh * 64 + e];
    vals[e] = v;
    m = fmaxf(m, v);
  }
  float s = 0.f;
#pragma unroll
  for (int e = 0; e < 64; ++e) { vals[e] = __expf(vals[e] - m); s += vals[e]; }
  float r = 1.0f / s;
#pragma unroll
  for (int e = 0; e < 64; ++e) row[e] = vals[e] * r;
}

// ---------------- K5: x_ca via MFMA ----------------
__global__ __launch_bounds__(256) void k_xca_mfma(
    const __hip_bfloat16* __restrict__ QKVV, const float* __restrict__ G,
    float* __restrict__ out) {
  const int bh = blockIdx.y, b = bh >> 3, h = bh & 7;
  const int nblk = blockIdx.x * 512;
  const int t = threadIdx.x, w = t >> 6, lane = t & 63;
  const int l15 = lane & 15, g = lane >> 4;
  bf16x8 Bf[4][2];
#pragma unroll
  for (int dt = 0; dt < 4; ++dt)
#pragma unroll
    for (int s = 0; s < 2; ++s) {
      const float* gp = &G[(size_t)bh * 4096 + (dt * 16 + l15) * 64 + s * 32 + g * 8];
      float4 v0 = *reinterpret_cast<const float4*>(gp);
      float4 v1 = *reinterpret_cast<const float4*>(gp + 4);
      bf16x8 bb;
      bb[0] = (short)bf16bits(v0.x); bb[1] = (short)bf16bits(v0.y);
      bb[2] = (short)bf16bits(v0.z); bb[3] = (short)bf16bits(v0.w);
      bb[4] = (short)bf16bits(v1.x); bb[5] = (short)bf16bits(v1.y);
      bb[6] = (short)bf16bits(v1.z); bb[7] = (short)bf16bits(v1.w);
      Bf[dt][s] = bb;
    }
  const __hip_bfloat16* vbase = QKVV + (size_t)b * SEQ * FOURC + 2 * CH + h * HDIM;
  for (int c = w; c < 32; c += 4) {
    const int n0 = nblk + c * 16;
    bf16x8 vf[2];
#pragma unroll
    for (int s = 0; s < 2; ++s)
      vf[s] = *reinterpret_cast<const bf16x8*>(
          &vbase[(size_t)(n0 + l15) * FOURC + s * 32 + g * 8]);
    f32x4 o[4] = {};
#pragma unroll
    for (int dt = 0; dt < 4; ++dt) {
      o[dt] = __builtin_amdgcn_mfma_f32_16x16x32_bf16(vf[0], Bf[dt][0], o[dt], 0, 0, 0);
      o[dt] = __builtin_amdgcn_mfma_f32_16x16x32_bf16(vf[1], Bf[dt][1], o[dt], 0, 0, 0);
    }
#pragma unroll
    for (int dt = 0; dt < 4; ++dt)
#pragma unroll
      for (int r = 0; r < 4; ++r)
        out[((size_t)(b * SEQ + n0 + g * 4 + r)) * CH + h * HDIM + dt * 16 + l15] = o[dt][r];
  }
}

// ---------------- K6: k/v projections via MFMA (TN gemm over n) ----------------
__global__ __launch_bounds__(256) void k_proj_mfma(
    const __hip_bfloat16* __restrict__ QKVV,
    const __hip_bfloat16* __restrict__ Pt,   // [256][8192] bf16
    float* __restrict__ raw) {               // [32][2][64][256] f32
  __shared__ __hip_bfloat16 cT[2][64][40];   // transposed comp tiles [d][n]
  __shared__ __hip_bfloat16 pT[256][40];     // Pt tile [k][n]
  const int bh = blockIdx.y, b = bh >> 3, h = bh & 7;
  const int nbase = blockIdx.x * 1024;
  const int t = threadIdx.x, w = t >> 6, lane = t & 63;
  const int l15 = lane & 15, g = lane >> 4;
  const int comp = w >> 1, kh = w & 1;
  const int srow = t >> 3, sdq = (t & 7) * 8;
  f32x4 acc[4][8] = {};
  for (int n0 = nbase; n0 < nbase + 1024; n0 += 32) {
#pragma unroll
    for (int cc = 0; cc < 2; ++cc) {
      const int coff = cc ? 3 * CH : CH;
      uint4 u = *reinterpret_cast<const uint4*>(
          &QKVV[(size_t)(b * SEQ + n0 + srow) * FOURC + coff + h * HDIM + sdq]);
      const __hip_bfloat16* hp = reinterpret_cast<const __hip_bfloat16*>(&u);
#pragma unroll
      for (int j = 0; j < 8; ++j) cT[cc][sdq + j][srow] = hp[j];
    }
#pragma unroll
    for (int ps = 0; ps < 4; ++ps) {
      int k = ps * 64 + (t >> 2);
      int poff = (t & 3) * 8;
      *reinterpret_cast<uint4*>(&pT[k][poff]) =
          *reinterpret_cast<const uint4*>(&Pt[(size_t)k * SEQ + n0 + poff]);
    }
    __syncthreads();
    bf16x8 A[4], B[8];
#pragma unroll
    for (int dt = 0; dt < 4; ++dt)
      A[dt] = *reinterpret_cast<const bf16x8*>(&cT[comp][dt * 16 + l15][g * 8]);
#pragma unroll
    for (int kt = 0; kt < 8; ++kt)
      B[kt] = *reinterpret_cast<const bf16x8*>(&pT[(kh * 8 + kt) * 16 + l15][g * 8]);
#pragma unroll
    for (int dt = 0; dt < 4; ++dt)
#pragma unroll
      for (int kt = 0; kt < 8; ++kt)
        acc[dt][kt] = __builtin_amdgcn_mfma_f32_16x16x32_bf16(A[dt], B[kt], acc[dt][kt], 0, 0, 0);
    __syncthreads();
  }
  float* rp = raw + ((size_t)bh * 2 + comp) * (64 * 256);
#pragma unroll
  for (int dt = 0; dt < 4; ++dt)
#pragma unroll
    for (int kt = 0; kt < 8; ++kt)
#pragma unroll
      for (int r = 0; r < 4; ++r)
        atomicAdd(&rp[(dt * 16 + g * 4 + r) * 256 + (kh * 8 + kt) * 16 + l15],
                  acc[dt][kt][r]);
}

// ---------------- K6b: finalize projections -> scaled bf16, kpT transposed ----------------
__global__ __launch_bounds__(256) void k_projfin(
    const float* __restrict__ raw, const float* __restrict__ invq,
    const float* __restrict__ invk, const float* __restrict__ tsa,
    __hip_bfloat16* __restrict__ kpT, __hip_bfloat16* __restrict__ vpT) {
  const int bh = blockIdx.x, h = bh & 7;
  const int t = threadIdx.x;
  __shared__ float tile[64][65];
  const float ts = tsa[h];
  const float* r0 = raw + (size_t)bh * 2 * 16384;
  for (int kc = 0; kc < 4; ++kc) {
    for (int i = t; i < 4096; i += 256) {
      int d = i >> 6, kk = i & 63;
      tile[d][kk] = r0[d * 256 + kc * 64 + kk];
    }
    __syncthreads();
    for (int i = t; i < 4096; i += 256) {
      int kk = i >> 6, d = i & 63;
      float sc = invq[bh * 64 + d] * invk[bh * 64 + d] * ts;
      kpT[(size_t)bh * 16384 + (kc * 64 + kk) * 64 + d] = __float2bfloat16(tile[d][kk] * sc);
    }
    __syncthreads();
  }
  const float* r1 = r0 + 16384;
  for (int i = t; i < 16384; i += 256)
    vpT[(size_t)bh * 16384 + i] = __float2bfloat16(r1[i]);
}

// ---------------- K7: spatial attention via MFMA (flash-style) ----------------
__global__ __launch_bounds__(256) void k_xsa_mfma(
    const __hip_bfloat16* __restrict__ QKVV,
    const __hip_bfloat16* __restrict__ kpT,   // [32][256][64] scaled bf16
    const __hip_bfloat16* __restrict__ vpT,   // [32][64][256] bf16
    float* __restrict__ out) {
  __shared__ __hip_bfloat16 vs[64][264];
  __shared__ __hip_bfloat16 ps[4][16][264];
  const int bh = blockIdx.y, b = bh >> 3, h = bh & 7;
  const int nblk = blockIdx.x * 512;
  const int t = threadIdx.x, w = t >> 6, lane = t & 63;
  const int l15 = lane & 15, g = lane >> 4;
  for (int i = t; i < 2048; i += 256) {
    int d = i >> 5, k8 = (i & 31) * 8;
    *reinterpret_cast<uint4*>(&vs[d][k8]) =
        *reinterpret_cast<const uint4*>(&vpT[((size_t)bh * 64 + d) * 256 + k8]);
  }
  bf16x8 kA[2][16];
#pragma unroll
  for (int s = 0; s < 2; ++s)
#pragma unroll
    for (int f = 0; f < 16; ++f)
      kA[s][f] = *reinterpret_cast<const bf16x8*>(
          &kpT[((size_t)bh * 256 + f * 16 + l15) * 64 + s * 32 + g * 8]);
  __syncthreads();
  const __hip_bfloat16* qbase = QKVV + (size_t)b * SEQ * FOURC + h * HDIM;
  for (int c = w; c < 32; c += 4) {
    const int n0 = nblk + c * 16;
    bf16x8 qf[2];
#pragma unroll
    for (int s = 0; s < 2; ++s)
      qf[s] = *reinterpret_cast<const bf16x8*>(
          &qbase[(size_t)(n0 + l15) * FOURC + s * 32 + g * 8]);
    f32x4 acc[16] = {};
#pragma unroll
    for (int f = 0; f < 16; ++f) {
      acc[f] = __builtin_amdgcn_mfma_f32_16x16x32_bf16(kA[0][f], qf[0], acc[f], 0, 0, 0);
      acc[f] = __builtin_amdgcn_mfma_f32_16x16x32_bf16(kA[1][f], qf[1], acc[f], 0, 0, 0);
    }
    float m = -3.0e38f;
#pragma unroll
    for (int f = 0; f < 16; ++f)
#pragma unroll
      for (int r = 0; r < 4; ++r) m = fmaxf(m, acc[f][r]);
    m = fmaxf(m, __shfl_xor(m, 16));
    m = fmaxf(m, __shfl_xor(m, 32));
    float sum = 0.f;
#pragma unroll
    for (int f = 0; f < 16; ++f)
#pragma unroll
      for (int r = 0; r < 4; ++r) {
        float e = __expf(acc[f][r] - m);
        acc[f][r] = e; sum += e;
      }
    sum += __shfl_xor(sum, 16);
    sum += __shfl_xor(sum, 32);
    const float rinv = 1.0f / sum;
#pragma unroll
    for (int f = 0; f < 16; ++f) {
      uint2 pw;
      pw.x = packbf2(acc[f][0] * rinv, acc[f][1] * rinv);
      pw.y = packbf2(acc[f][2] * rinv, acc[f][3] * rinv);
      *reinterpret_cast<uint2*>(&ps[w][l15][f * 16 + g * 4]) = pw;
    }
    __builtin_amdgcn_wave_barrier();
    f32x4 o[4] = {};
#pragma unroll
    for (int s = 0; s < 8; ++s) {
      bf16x8 pa = *reinterpret_cast<const bf16x8*>(&ps[w][l15][s * 32 + g * 8]);
#pragma unroll
      for (int dt = 0; dt < 4; ++dt) {
        bf16x8 vb = *reinterpret_cast<const bf16x8*>(&vs[dt * 16 + l15][s * 32 + g * 8]);
        o[dt] = __builtin_amdgcn_mfma_f32_16x16x32_bf16(pa, vb, o[dt], 0, 0, 0);
      }
    }
#pragma unroll
    for (int dt = 0; dt < 4; ++dt)
#pragma unroll
      for (int r = 0; r < 4; ++r) {
        size_t oo = ((size_t)(b * SEQ + n0 + g * 4 + r)) * CH + h * HDIM + dt * 16 + l15;
        out[oo] += o[dt][r];
      }
    __builtin_amdgcn_wave_barrier();
  }
}

extern "C" void kernel_launch(void* const* d_in, const int* in_sizes, int n_in,
                              void* d_out, int out_size, void* d_ws, size_t ws_size,
                              hipStream_t stream) {
  const float* x   = (const float*)d_in[0];
  const float* w   = (const float*)d_in[1];
  const float* sp  = (const float*)d_in[2];
  const float* tca = (const float*)d_in[3];
  const float* tsa = (const float*)d_in[4];
  float* out = (float*)d_out;
  char* ws = (char*)d_ws;

  __hip_bfloat16* qkvv = (__hip_bfloat16*)ws;                  // 134217728
  __hip_bfloat16* wt   = (__hip_bfloat16*)(ws + 134217728);    // 2097152
  float* G     = (float*)(ws + 136314880);                     // 524288
  float* sumsq = (float*)(ws + 136839168);                     // 16384
  float* invq  = (float*)(ws + 136855552);                     // 8192
  float* invk  = (float*)(ws + 136863744);                     // 8192
  __hip_bfloat16* pt   = (__hip_bfloat16*)(ws + 136871936);    // 4194304
  __hip_bfloat16* kpT  = (__hip_bfloat16*)(ws + 141066240);    // 1048576
  __hip_bfloat16* vpT  = (__hip_bfloat16*)(ws + 142114816);    // 1048576
  float* raw   = (float*)(ws + 143163392);                     // 4194304

  hipMemsetAsync(G, 0, 524288, stream);
  hipMemsetAsync(sumsq, 0, 16384, stream);
  hipMemsetAsync(raw, 0, 4194304, stream);

  hipLaunchKernelGGL(k_wt, dim3(64, 16), dim3(256), 0, stream, w, wt);
  hipLaunchKernelGGL(k_pt, dim3(256, 8), dim3(256), 0, stream, sp, pt);
  hipLaunchKernelGGL(k_gemm_mfma, dim3(16, 256), dim3(256), 0, stream, x, wt, qkvv);
  hipLaunchKernelGGL(k_norms2, dim3(32, 32), dim3(256), 0, stream, qkvv, sumsq);
  hipLaunchKernelGGL(k_finalize, dim3(8), dim3(256), 0, stream, sumsq, invq, invk);
  hipLaunchKernelGGL(k_gram, dim3(32, 8), dim3(256), 0, stream, qkvv, G);
  hipLaunchKernelGGL(k_ca_softmax, dim3(32), dim3(64), 0, stream, G, invq, invk, tca);
  hipLaunchKernelGGL(k_proj_mfma, dim3(8, 32), dim3(256), 0, stream, qkvv, pt, raw);
  hipLaunchKernelGGL(k_projfin, dim3(32), dim3(256), 0, stream, raw, invq, invk, tsa, kpT, vpT);
  hipLaunchKernelGGL(k_xca_mfma, dim3(16, 32), dim3(256), 0, stream, qkvv, G, out);
  hipLaunchKernelGGL(k_xsa_mfma, dim3(16, 32), dim3(256), 0, stream, qkvv, kpT, vpT, out);
}

// Round 4
// 368.676 us; speedup vs baseline: 9.7202x; 1.1476x over previous
//
#include <hip/hip_runtime.h>
#include <hip/hip_bf16.h>

#define BATCH 4
#define SEQ   8192
#define CH    512
#define NHEAD 8
#define HDIM  64
#define KTOK  256
#define FOURC 2048

typedef __attribute__((ext_vector_type(8))) short bf16x8;
typedef __attribute__((ext_vector_type(4))) float f32x4;

#define GLOAD_LDS16(g, l)                                                      \
  __builtin_amdgcn_global_load_lds(                                            \
      (const __attribute__((address_space(1))) void*)(g),                      \
      (__attribute__((address_space(3))) void*)(l), 16, 0, 0)

__device__ __forceinline__ void expand8(uint4 u, float* f) {
  f[0] = __uint_as_float(u.x << 16); f[1] = __uint_as_float(u.x & 0xffff0000u);
  f[2] = __uint_as_float(u.y << 16); f[3] = __uint_as_float(u.y & 0xffff0000u);
  f[4] = __uint_as_float(u.z << 16); f[5] = __uint_as_float(u.z & 0xffff0000u);
  f[6] = __uint_as_float(u.w << 16); f[7] = __uint_as_float(u.w & 0xffff0000u);
}

__device__ __forceinline__ ushort bf16bits(float f) {
  __hip_bfloat16 b = __float2bfloat16(f);
  return *reinterpret_cast<ushort*>(&b);
}
__device__ __forceinline__ uint packbf2(float lo, float hi) {
  return (uint)bf16bits(lo) | ((uint)bf16bits(hi) << 16);
}

// ---------------- K0: W [512][2048] fp32 -> Wt [2048][512] bf16 ----------------
__global__ __launch_bounds__(256) void k_wt(
    const float* __restrict__ W, __hip_bfloat16* __restrict__ Wt) {
  __shared__ float tile[32][33];
  const int bx = blockIdx.x * 32;
  const int by = blockIdx.y * 32;
  const int t = threadIdx.x;
  const int r = t >> 5, c = t & 31;
#pragma unroll
  for (int it = 0; it < 4; ++it)
    tile[r + it * 8][c] = W[(size_t)(by + r + it * 8) * FOURC + bx + c];
  __syncthreads();
#pragma unroll
  for (int it = 0; it < 4; ++it) {
    int n = r + it * 8;
    Wt[(size_t)(bx + n) * CH + by + c] = __float2bfloat16(tile[c][n]);
  }
}

// ---------------- K0b: P [8192][256] fp32 -> Pt [256][8192] bf16 ----------------
__global__ __launch_bounds__(256) void k_pt(
    const float* __restrict__ P, __hip_bfloat16* __restrict__ Pt) {
  __shared__ float tile[32][33];
  const int n0 = blockIdx.x * 32, k0 = blockIdx.y * 32;
  const int t = threadIdx.x, r = t >> 5, c = t & 31;
#pragma unroll
  for (int i = 0; i < 4; ++i)
    tile[r + i * 8][c] = P[(size_t)(n0 + r + i * 8) * KTOK + k0 + c];
  __syncthreads();
#pragma unroll
  for (int i = 0; i < 4; ++i)
    Pt[(size_t)(k0 + r + i * 8) * SEQ + n0 + c] = __float2bfloat16(tile[c][r + i * 8]);
}

// ---------------- K0c: X fp32 -> Xb bf16 (flat stream) ----------------
__global__ __launch_bounds__(256) void k_xbf(
    const float* __restrict__ X, __hip_bfloat16* __restrict__ Xb) {
  size_t i = ((size_t)blockIdx.x * 256 + threadIdx.x) * 8;
  float4 a = *reinterpret_cast<const float4*>(&X[i]);
  float4 b = *reinterpret_cast<const float4*>(&X[i + 4]);
  ushort tmp[8];
  tmp[0] = bf16bits(a.x); tmp[1] = bf16bits(a.y);
  tmp[2] = bf16bits(a.z); tmp[3] = bf16bits(a.w);
  tmp[4] = bf16bits(b.x); tmp[5] = bf16bits(b.y);
  tmp[6] = bf16bits(b.z); tmp[7] = bf16bits(b.w);
  *reinterpret_cast<uint4*>(&Xb[i]) = *reinterpret_cast<const uint4*>(tmp);
}

// ---------------- K1: qkvv = Xb @ Wt via bf16 MFMA + global_load_lds ----------------
__global__ __launch_bounds__(256) void k_gemm_mfma(
    const __hip_bfloat16* __restrict__ Xb, const __hip_bfloat16* __restrict__ Wt,
    __hip_bfloat16* __restrict__ QKVV) {
  __shared__ __align__(16) __hip_bfloat16 As[128 * 32];  // [m][k]
  __shared__ __align__(16) __hip_bfloat16 Bs[128 * 32];  // [n][k]
  const int t = threadIdx.x;
  const int wid = t >> 6, lane = t & 63;
  // XCD-chunked bijective swizzle over 4096 blocks (4096 % 8 == 0)
  const int bid = blockIdx.x;
  const int swz = (bid & 7) * 512 + (bid >> 3);
  const int bn = (swz >> 8) * 128;   // 16 column panels
  const int bm = (swz & 255) * 128;  // 256 row panels
  const int wr = wid >> 1, wc = wid & 1;
  const int lrow = lane & 15, lk = (lane >> 4) * 8;
  const int srow = lane >> 2;        // 0..15 row within 16-row chunk
  const int sk8 = (lane & 3) * 8;    // k-offset (elements)
  f32x4 acc[4][4] = {};
  for (int k0 = 0; k0 < CH; k0 += 32) {
#pragma unroll
    for (int i = 0; i < 2; ++i) {
      const int c = wid * 2 + i;     // 0..7 chunk of 16 rows
      GLOAD_LDS16(&Xb[(size_t)(bm + c * 16 + srow) * CH + k0 + sk8], &As[c * 512]);
      GLOAD_LDS16(&Wt[(size_t)(bn + c * 16 + srow) * CH + k0 + sk8], &Bs[c * 512]);
    }
    __syncthreads();
    bf16x8 af[4], bfr[4];
#pragma unroll
    for (int i = 0; i < 4; ++i)
      af[i] = *reinterpret_cast<const bf16x8*>(&As[(wr * 64 + i * 16 + lrow) * 32 + lk]);
#pragma unroll
    for (int j = 0; j < 4; ++j)
      bfr[j] = *reinterpret_cast<const bf16x8*>(&Bs[(wc * 64 + j * 16 + lrow) * 32 + lk]);
#pragma unroll
    for (int i = 0; i < 4; ++i)
#pragma unroll
      for (int j = 0; j < 4; ++j)
        acc[i][j] = __builtin_amdgcn_mfma_f32_16x16x32_bf16(af[i], bfr[j], acc[i][j], 0, 0, 0);
    __syncthreads();
  }
  const int l4 = (lane >> 4) * 4;
#pragma unroll
  for (int i = 0; i < 4; ++i)
#pragma unroll
    for (int j = 0; j < 4; ++j) {
      int col = bn + wc * 64 + j * 16 + lrow;
#pragma unroll
      for (int r = 0; r < 4; ++r) {
        int row = bm + wr * 64 + i * 16 + l4 + r;
        QKVV[(size_t)row * FOURC + col] = __float2bfloat16(acc[i][j][r]);
      }
    }
}

// ---------------- K2: sum-of-squares over tokens ----------------
__global__ __launch_bounds__(256) void k_norms2(
    const __hip_bfloat16* __restrict__ QKVV, float* __restrict__ sumsq) {
  const int bh = blockIdx.y, b = bh >> 3, h = bh & 7;
  const int n0 = blockIdx.x * 256;
  const int t = threadIdx.x;
  const int rt = t >> 3, cg = t & 7;
  __shared__ float red[32][64];
#pragma unroll
  for (int comp = 0; comp < 2; ++comp) {
    float s[8] = {};
    const size_t base = (size_t)(b * SEQ + n0) * FOURC + comp * CH + h * HDIM + cg * 8;
    for (int r = rt; r < 256; r += 32) {
      uint4 u = *reinterpret_cast<const uint4*>(&QKVV[base + (size_t)r * FOURC]);
      float f[8]; expand8(u, f);
#pragma unroll
      for (int j = 0; j < 8; ++j) s[j] = fmaf(f[j], f[j], s[j]);
    }
#pragma unroll
    for (int j = 0; j < 8; ++j) red[rt][cg * 8 + j] = s[j];
    __syncthreads();
    if (t < 64) {
      float tot = 0.f;
#pragma unroll
      for (int r = 0; r < 32; ++r) tot += red[r][t];
      atomicAdd(&sumsq[comp * 2048 + bh * 64 + t], tot);
    }
    __syncthreads();
  }
}

__global__ __launch_bounds__(256) void k_finalize(
    const float* __restrict__ sumsq, float* __restrict__ invq, float* __restrict__ invk) {
  int i = blockIdx.x * 256 + threadIdx.x;
  if (i < 2048) {
    invq[i] = rsqrtf(fmaxf(sumsq[i], 1e-6f));
    invk[i] = rsqrtf(fmaxf(sumsq[2048 + i], 1e-6f));
  }
}

// ---------------- K3: gram via MFMA (TN over n) ----------------
__global__ __launch_bounds__(256) void k_gram_mfma(
    const __hip_bfloat16* __restrict__ QKVV, float* __restrict__ G) {
  __shared__ __hip_bfloat16 qT[64][40];
  __shared__ __hip_bfloat16 kT[64][40];
  const int bh = blockIdx.y, b = bh >> 3, h = bh & 7;
  const int nbase = blockIdx.x * 1024;
  const int t = threadIdx.x, w = t >> 6, lane = t & 63;
  const int l15 = lane & 15, g = lane >> 4;
  const int srow = t >> 3, sdq = (t & 7) * 8;
  f32x4 acc[4] = {};
  for (int n0 = nbase; n0 < nbase + 1024; n0 += 32) {
    size_t gb = (size_t)(b * SEQ + n0 + srow) * FOURC + h * HDIM + sdq;
    uint4 uq = *reinterpret_cast<const uint4*>(&QKVV[gb]);
    uint4 uk = *reinterpret_cast<const uint4*>(&QKVV[gb + CH]);
    const __hip_bfloat16* hq = reinterpret_cast<const __hip_bfloat16*>(&uq);
    const __hip_bfloat16* hk = reinterpret_cast<const __hip_bfloat16*>(&uk);
#pragma unroll
    for (int j = 0; j < 8; ++j) { qT[sdq + j][srow] = hq[j]; kT[sdq + j][srow] = hk[j]; }
    __syncthreads();
    bf16x8 A[4];
#pragma unroll
    for (int dt = 0; dt < 4; ++dt)
      A[dt] = *reinterpret_cast<const bf16x8*>(&qT[dt * 16 + l15][g * 8]);
    bf16x8 B = *reinterpret_cast<const bf16x8*>(&kT[w * 16 + l15][g * 8]);
#pragma unroll
    for (int dt = 0; dt < 4; ++dt)
      acc[dt] = __builtin_amdgcn_mfma_f32_16x16x32_bf16(A[dt], B, acc[dt], 0, 0, 0);
    __syncthreads();
  }
  float* gp = G + (size_t)bh * 4096;
#pragma unroll
  for (int dt = 0; dt < 4; ++dt)
#pragma unroll
    for (int r = 0; r < 4; ++r)
      atomicAdd(&gp[(dt * 16 + g * 4 + r) * 64 + w * 16 + l15], acc[dt][r]);
}

// ---------------- K4: channel-attention softmax ----------------
__global__ __launch_bounds__(64) void k_ca_softmax(
    float* __restrict__ G, const float* __restrict__ invq,
    const float* __restrict__ invk, const float* __restrict__ tca) {
  const int bh = blockIdx.x, h = bh & 7;
  const int d = threadIdx.x;
  float* row = G + (size_t)bh * 4096 + d * 64;
  const float s0 = invq[bh * 64 + d] * tca[h];
  float vals[64];
  float m = -3.0e38f;
#pragma unroll
  for (int e = 0; e < 64; ++e) {
    float v = row[e] * s0 * invk[bh * 64 + e];
    vals[e] = v;
    m = fmaxf(m, v);
  }
  float s = 0.f;
#pragma unroll
  for (int e = 0; e < 64; ++e) { vals[e] = __expf(vals[e] - m); s += vals[e]; }
  float r = 1.0f / s;
#pragma unroll
  for (int e = 0; e < 64; ++e) row[e] = vals[e] * r;
}

// ---------------- K5: x_ca via MFMA ----------------
__global__ __launch_bounds__(256) void k_xca_mfma(
    const __hip_bfloat16* __restrict__ QKVV, const float* __restrict__ G,
    float* __restrict__ out) {
  const int bh = blockIdx.y, b = bh >> 3, h = bh & 7;
  const int nblk = blockIdx.x * 512;
  const int t = threadIdx.x, w = t >> 6, lane = t & 63;
  const int l15 = lane & 15, g = lane >> 4;
  bf16x8 Bf[4][2];
#pragma unroll
  for (int dt = 0; dt < 4; ++dt)
#pragma unroll
    for (int s = 0; s < 2; ++s) {
      const float* gp = &G[(size_t)bh * 4096 + (dt * 16 + l15) * 64 + s * 32 + g * 8];
      float4 v0 = *reinterpret_cast<const float4*>(gp);
      float4 v1 = *reinterpret_cast<const float4*>(gp + 4);
      bf16x8 bb;
      bb[0] = (short)bf16bits(v0.x); bb[1] = (short)bf16bits(v0.y);
      bb[2] = (short)bf16bits(v0.z); bb[3] = (short)bf16bits(v0.w);
      bb[4] = (short)bf16bits(v1.x); bb[5] = (short)bf16bits(v1.y);
      bb[6] = (short)bf16bits(v1.z); bb[7] = (short)bf16bits(v1.w);
      Bf[dt][s] = bb;
    }
  const __hip_bfloat16* vbase = QKVV + (size_t)b * SEQ * FOURC + 2 * CH + h * HDIM;
  for (int c = w; c < 32; c += 4) {
    const int n0 = nblk + c * 16;
    bf16x8 vf[2];
#pragma unroll
    for (int s = 0; s < 2; ++s)
      vf[s] = *reinterpret_cast<const bf16x8*>(
          &vbase[(size_t)(n0 + l15) * FOURC + s * 32 + g * 8]);
    f32x4 o[4] = {};
#pragma unroll
    for (int dt = 0; dt < 4; ++dt) {
      o[dt] = __builtin_amdgcn_mfma_f32_16x16x32_bf16(vf[0], Bf[dt][0], o[dt], 0, 0, 0);
      o[dt] = __builtin_amdgcn_mfma_f32_16x16x32_bf16(vf[1], Bf[dt][1], o[dt], 0, 0, 0);
    }
#pragma unroll
    for (int dt = 0; dt < 4; ++dt)
#pragma unroll
      for (int r = 0; r < 4; ++r)
        out[((size_t)(b * SEQ + n0 + g * 4 + r)) * CH + h * HDIM + dt * 16 + l15] = o[dt][r];
  }
}

// ---------------- K6: k/v projections via MFMA ----------------
__global__ __launch_bounds__(256) void k_proj_mfma(
    const __hip_bfloat16* __restrict__ QKVV,
    const __hip_bfloat16* __restrict__ Pt,
    float* __restrict__ raw) {
  __shared__ __hip_bfloat16 cT[2][64][40];
  __shared__ __hip_bfloat16 pT[256][40];
  const int bh = blockIdx.y, b = bh >> 3, h = bh & 7;
  const int nbase = blockIdx.x * 1024;
  const int t = threadIdx.x, w = t >> 6, lane = t & 63;
  const int l15 = lane & 15, g = lane >> 4;
  const int comp = w >> 1, kh = w & 1;
  const int srow = t >> 3, sdq = (t & 7) * 8;
  f32x4 acc[4][8] = {};
  for (int n0 = nbase; n0 < nbase + 1024; n0 += 32) {
#pragma unroll
    for (int cc = 0; cc < 2; ++cc) {
      const int coff = cc ? 3 * CH : CH;
      uint4 u = *reinterpret_cast<const uint4*>(
          &QKVV[(size_t)(b * SEQ + n0 + srow) * FOURC + coff + h * HDIM + sdq]);
      const __hip_bfloat16* hp = reinterpret_cast<const __hip_bfloat16*>(&u);
#pragma unroll
      for (int j = 0; j < 8; ++j) cT[cc][sdq + j][srow] = hp[j];
    }
#pragma unroll
    for (int ps = 0; ps < 4; ++ps) {
      int k = ps * 64 + (t >> 2);
      int poff = (t & 3) * 8;
      *reinterpret_cast<uint4*>(&pT[k][poff]) =
          *reinterpret_cast<const uint4*>(&Pt[(size_t)k * SEQ + n0 + poff]);
    }
    __syncthreads();
    bf16x8 A[4], B[8];
#pragma unroll
    for (int dt = 0; dt < 4; ++dt)
      A[dt] = *reinterpret_cast<const bf16x8*>(&cT[comp][dt * 16 + l15][g * 8]);
#pragma unroll
    for (int kt = 0; kt < 8; ++kt)
      B[kt] = *reinterpret_cast<const bf16x8*>(&pT[(kh * 8 + kt) * 16 + l15][g * 8]);
#pragma unroll
    for (int dt = 0; dt < 4; ++dt)
#pragma unroll
      for (int kt = 0; kt < 8; ++kt)
        acc[dt][kt] = __builtin_amdgcn_mfma_f32_16x16x32_bf16(A[dt], B[kt], acc[dt][kt], 0, 0, 0);
    __syncthreads();
  }
  float* rp = raw + ((size_t)bh * 2 + comp) * (64 * 256);
#pragma unroll
  for (int dt = 0; dt < 4; ++dt)
#pragma unroll
    for (int kt = 0; kt < 8; ++kt)
#pragma unroll
      for (int r = 0; r < 4; ++r)
        atomicAdd(&rp[(dt * 16 + g * 4 + r) * 256 + (kh * 8 + kt) * 16 + l15],
                  acc[dt][kt][r]);
}

// ---------------- K6b: finalize projections ----------------
__global__ __launch_bounds__(256) void k_projfin(
    const float* __restrict__ raw, const float* __restrict__ invq,
    const float* __restrict__ invk, const float* __restrict__ tsa,
    __hip_bfloat16* __restrict__ kpT, __hip_bfloat16* __restrict__ vpT) {
  const int bh = blockIdx.x, h = bh & 7;
  const int t = threadIdx.x;
  __shared__ float tile[64][65];
  const float ts = tsa[h];
  const float* r0 = raw + (size_t)bh * 2 * 16384;
  for (int kc = 0; kc < 4; ++kc) {
    for (int i = t; i < 4096; i += 256) {
      int d = i >> 6, kk = i & 63;
      tile[d][kk] = r0[d * 256 + kc * 64 + kk];
    }
    __syncthreads();
    for (int i = t; i < 4096; i += 256) {
      int kk = i >> 6, d = i & 63;
      float sc = invq[bh * 64 + d] * invk[bh * 64 + d] * ts;
      kpT[(size_t)bh * 16384 + (kc * 64 + kk) * 64 + d] = __float2bfloat16(tile[d][kk] * sc);
    }
    __syncthreads();
  }
  const float* r1 = r0 + 16384;
  for (int i = t; i < 16384; i += 256)
    vpT[(size_t)bh * 16384 + i] = __float2bfloat16(r1[i]);
}

// ---------------- K7: spatial attention via MFMA ----------------
__global__ __launch_bounds__(256) void k_xsa_mfma(
    const __hip_bfloat16* __restrict__ QKVV,
    const __hip_bfloat16* __restrict__ kpT,
    const __hip_bfloat16* __restrict__ vpT,
    float* __restrict__ out) {
  __shared__ __hip_bfloat16 vs[64][264];
  __shared__ __hip_bfloat16 ps[4][16][264];
  const int bh = blockIdx.y, b = bh >> 3, h = bh & 7;
  const int nblk = blockIdx.x * 512;
  const int t = threadIdx.x, w = t >> 6, lane = t & 63;
  const int l15 = lane & 15, g = lane >> 4;
  for (int i = t; i < 2048; i += 256) {
    int d = i >> 5, k8 = (i & 31) * 8;
    *reinterpret_cast<uint4*>(&vs[d][k8]) =
        *reinterpret_cast<const uint4*>(&vpT[((size_t)bh * 64 + d) * 256 + k8]);
  }
  bf16x8 kA[2][16];
#pragma unroll
  for (int s = 0; s < 2; ++s)
#pragma unroll
    for (int f = 0; f < 16; ++f)
      kA[s][f] = *reinterpret_cast<const bf16x8*>(
          &kpT[((size_t)bh * 256 + f * 16 + l15) * 64 + s * 32 + g * 8]);
  __syncthreads();
  const __hip_bfloat16* qbase = QKVV + (size_t)b * SEQ * FOURC + h * HDIM;
  for (int c = w; c < 32; c += 4) {
    const int n0 = nblk + c * 16;
    bf16x8 qf[2];
#pragma unroll
    for (int s = 0; s < 2; ++s)
      qf[s] = *reinterpret_cast<const bf16x8*>(
          &qbase[(size_t)(n0 + l15) * FOURC + s * 32 + g * 8]);
    f32x4 acc[16] = {};
#pragma unroll
    for (int f = 0; f < 16; ++f) {
      acc[f] = __builtin_amdgcn_mfma_f32_16x16x32_bf16(kA[0][f], qf[0], acc[f], 0, 0, 0);
      acc[f] = __builtin_amdgcn_mfma_f32_16x16x32_bf16(kA[1][f], qf[1], acc[f], 0, 0, 0);
    }
    float m = -3.0e38f;
#pragma unroll
    for (int f = 0; f < 16; ++f)
#pragma unroll
      for (int r = 0; r < 4; ++r) m = fmaxf(m, acc[f][r]);
    m = fmaxf(m, __shfl_xor(m, 16));
    m = fmaxf(m, __shfl_xor(m, 32));
    float sum = 0.f;
#pragma unroll
    for (int f = 0; f < 16; ++f)
#pragma unroll
      for (int r = 0; r < 4; ++r) {
        float e = __expf(acc[f][r] - m);
        acc[f][r] = e; sum += e;
      }
    sum += __shfl_xor(sum, 16);
    sum += __shfl_xor(sum, 32);
    const float rinv = 1.0f / sum;
#pragma unroll
    for (int f = 0; f < 16; ++f) {
      uint2 pw;
      pw.x = packbf2(acc[f][0] * rinv, acc[f][1] * rinv);
      pw.y = packbf2(acc[f][2] * rinv, acc[f][3] * rinv);
      *reinterpret_cast<uint2*>(&ps[w][l15][f * 16 + g * 4]) = pw;
    }
    __builtin_amdgcn_wave_barrier();
    f32x4 o[4] = {};
#pragma unroll
    for (int s = 0; s < 8; ++s) {
      bf16x8 pa = *reinterpret_cast<const bf16x8*>(&ps[w][l15][s * 32 + g * 8]);
#pragma unroll
      for (int dt = 0; dt < 4; ++dt) {
        bf16x8 vb = *reinterpret_cast<const bf16x8*>(&vs[dt * 16 + l15][s * 32 + g * 8]);
        o[dt] = __builtin_amdgcn_mfma_f32_16x16x32_bf16(pa, vb, o[dt], 0, 0, 0);
      }
    }
#pragma unroll
    for (int dt = 0; dt < 4; ++dt)
#pragma unroll
      for (int r = 0; r < 4; ++r) {
        size_t oo = ((size_t)(b * SEQ + n0 + g * 4 + r)) * CH + h * HDIM + dt * 16 + l15;
        out[oo] += o[dt][r];
      }
    __builtin_amdgcn_wave_barrier();
  }
}

extern "C" void kernel_launch(void* const* d_in, const int* in_sizes, int n_in,
                              void* d_out, int out_size, void* d_ws, size_t ws_size,
                              hipStream_t stream) {
  const float* x   = (const float*)d_in[0];
  const float* w   = (const float*)d_in[1];
  const float* sp  = (const float*)d_in[2];
  const float* tca = (const float*)d_in[3];
  const float* tsa = (const float*)d_in[4];
  float* out = (float*)d_out;
  char* ws = (char*)d_ws;

  __hip_bfloat16* qkvv = (__hip_bfloat16*)ws;                  // 134217728
  __hip_bfloat16* wt   = (__hip_bfloat16*)(ws + 134217728);    // 2097152
  float* G     = (float*)(ws + 136314880);                     // 524288
  float* sumsq = (float*)(ws + 136839168);                     // 16384
  float* invq  = (float*)(ws + 136855552);                     // 8192
  float* invk  = (float*)(ws + 136863744);                     // 8192
  __hip_bfloat16* pt   = (__hip_bfloat16*)(ws + 136871936);    // 4194304
  __hip_bfloat16* kpT  = (__hip_bfloat16*)(ws + 141066240);    // 1048576
  __hip_bfloat16* vpT  = (__hip_bfloat16*)(ws + 142114816);    // 1048576
  float* raw   = (float*)(ws + 143163392);                     // 4194304
  __hip_bfloat16* xb   = (__hip_bfloat16*)(ws + 147357696);    // 33554432

  hipMemsetAsync(G, 0, 524288, stream);
  hipMemsetAsync(sumsq, 0, 16384, stream);
  hipMemsetAsync(raw, 0, 4194304, stream);

  hipLaunchKernelGGL(k_wt, dim3(64, 16), dim3(256), 0, stream, w, wt);
  hipLaunchKernelGGL(k_pt, dim3(256, 8), dim3(256), 0, stream, sp, pt);
  hipLaunchKernelGGL(k_xbf, dim3(8192), dim3(256), 0, stream, x, xb);
  hipLaunchKernelGGL(k_gemm_mfma, dim3(4096), dim3(256), 0, stream, xb, wt, qkvv);
  hipLaunchKernelGGL(k_norms2, dim3(32, 32), dim3(256), 0, stream, qkvv, sumsq);
  hipLaunchKernelGGL(k_finalize, dim3(8), dim3(256), 0, stream, sumsq, invq, invk);
  hipLaunchKernelGGL(k_gram_mfma, dim3(8, 32), dim3(256), 0, stream, qkvv, G);
  hipLaunchKernelGGL(k_ca_softmax, dim3(32), dim3(64), 0, stream, G, invq, invk, tca);
  hipLaunchKernelGGL(k_proj_mfma, dim3(8, 32), dim3(256), 0, stream, qkvv, pt, raw);
  hipLaunchKernelGGL(k_projfin, dim3(32), dim3(256), 0, stream, raw, invq, invk, tsa, kpT, vpT);
  hipLaunchKernelGGL(k_xca_mfma, dim3(16, 32), dim3(256), 0, stream, qkvv, G, out);
  hipLaunchKernelGGL(k_xsa_mfma, dim3(16, 32), dim3(256), 0, stream, qkvv, kpT, vpT, out);
}

// Round 5
// 310.396 us; speedup vs baseline: 11.5453x; 1.1878x over previous
//
#include <hip/hip_runtime.h>
#include <hip/hip_bf16.h>

#define BATCH 4
#define SEQ   8192
#define CH    512
#define NHEAD 8
#define HDIM  64
#define KTOK  256
#define FOURC 2048

typedef __attribute__((ext_vector_type(8))) short bf16x8;
typedef __attribute__((ext_vector_type(4))) float f32x4;

#define GLOAD_LDS16(g, l)                                                      \
  __builtin_amdgcn_global_load_lds(                                            \
      (const __attribute__((address_space(1))) void*)(g),                      \
      (__attribute__((address_space(3))) void*)(l), 16, 0, 0)

__device__ __forceinline__ ushort bf16bits(float f) {
  __hip_bfloat16 b = __float2bfloat16(f);
  return *reinterpret_cast<ushort*>(&b);
}
__device__ __forceinline__ uint packbf2(float lo, float hi) {
  return (uint)bf16bits(lo) | ((uint)bf16bits(hi) << 16);
}

// ---------------- K0: W [512][2048] fp32 -> Wt [2048][512] bf16 ----------------
__global__ __launch_bounds__(256) void k_wt(
    const float* __restrict__ W, __hip_bfloat16* __restrict__ Wt) {
  __shared__ float tile[32][33];
  const int bx = blockIdx.x * 32;
  const int by = blockIdx.y * 32;
  const int t = threadIdx.x;
  const int r = t >> 5, c = t & 31;
#pragma unroll
  for (int it = 0; it < 4; ++it)
    tile[r + it * 8][c] = W[(size_t)(by + r + it * 8) * FOURC + bx + c];
  __syncthreads();
#pragma unroll
  for (int it = 0; it < 4; ++it) {
    int n = r + it * 8;
    Wt[(size_t)(bx + n) * CH + by + c] = __float2bfloat16(tile[c][n]);
  }
}

// ---------------- K0b: P [8192][256] fp32 -> Pt [256][8192] bf16 ----------------
__global__ __launch_bounds__(256) void k_pt(
    const float* __restrict__ P, __hip_bfloat16* __restrict__ Pt) {
  __shared__ float tile[32][33];
  const int n0 = blockIdx.x * 32, k0 = blockIdx.y * 32;
  const int t = threadIdx.x, r = t >> 5, c = t & 31;
#pragma unroll
  for (int i = 0; i < 4; ++i)
    tile[r + i * 8][c] = P[(size_t)(n0 + r + i * 8) * KTOK + k0 + c];
  __syncthreads();
#pragma unroll
  for (int i = 0; i < 4; ++i)
    Pt[(size_t)(k0 + r + i * 8) * SEQ + n0 + c] = __float2bfloat16(tile[c][r + i * 8]);
}

// ---------------- K0c: X fp32 -> Xb bf16 (flat stream) ----------------
__global__ __launch_bounds__(256) void k_xbf(
    const float* __restrict__ X, __hip_bfloat16* __restrict__ Xb) {
  size_t i = ((size_t)blockIdx.x * 256 + threadIdx.x) * 8;
  float4 a = *reinterpret_cast<const float4*>(&X[i]);
  float4 b = *reinterpret_cast<const float4*>(&X[i + 4]);
  ushort tmp[8];
  tmp[0] = bf16bits(a.x); tmp[1] = bf16bits(a.y);
  tmp[2] = bf16bits(a.z); tmp[3] = bf16bits(a.w);
  tmp[4] = bf16bits(b.x); tmp[5] = bf16bits(b.y);
  tmp[6] = bf16bits(b.z); tmp[7] = bf16bits(b.w);
  *reinterpret_cast<uint4*>(&Xb[i]) = *reinterpret_cast<const uint4*>(tmp);
}

// ---------------- K1: qkvv = Xb @ Wt via bf16 MFMA + global_load_lds ----------------
// XCD-aware: each XCD owns 32 contiguous bm panels (4MB Xb slice, L2-resident);
// bn sweeps fastest so Wt (2MB) stays L2-resident per XCD.
__global__ __launch_bounds__(256) void k_gemm_mfma(
    const __hip_bfloat16* __restrict__ Xb, const __hip_bfloat16* __restrict__ Wt,
    __hip_bfloat16* __restrict__ QKVV) {
  __shared__ __align__(16) __hip_bfloat16 As[128 * 32];  // [m][k]
  __shared__ __align__(16) __hip_bfloat16 Bs[128 * 32];  // [n][k]
  const int t = threadIdx.x;
  const int wid = t >> 6, lane = t & 63;
  const int bid = blockIdx.x;
  const int xcd = bid & 7;
  const int l = bid >> 3;                 // 0..511
  const int bm = (xcd * 32 + (l >> 4)) * 128;
  const int bn = (l & 15) * 128;
  const int wr = wid >> 1, wc = wid & 1;
  const int lrow = lane & 15, lk = (lane >> 4) * 8;
  const int srow = lane >> 2;
  const int sk8 = (lane & 3) * 8;
  f32x4 acc[4][4] = {};
  for (int k0 = 0; k0 < CH; k0 += 32) {
#pragma unroll
    for (int i = 0; i < 2; ++i) {
      const int c = wid * 2 + i;
      GLOAD_LDS16(&Xb[(size_t)(bm + c * 16 + srow) * CH + k0 + sk8], &As[c * 512]);
      GLOAD_LDS16(&Wt[(size_t)(bn + c * 16 + srow) * CH + k0 + sk8], &Bs[c * 512]);
    }
    __syncthreads();
    bf16x8 af[4], bfr[4];
#pragma unroll
    for (int i = 0; i < 4; ++i)
      af[i] = *reinterpret_cast<const bf16x8*>(&As[(wr * 64 + i * 16 + lrow) * 32 + lk]);
#pragma unroll
    for (int j = 0; j < 4; ++j)
      bfr[j] = *reinterpret_cast<const bf16x8*>(&Bs[(wc * 64 + j * 16 + lrow) * 32 + lk]);
#pragma unroll
    for (int i = 0; i < 4; ++i)
#pragma unroll
      for (int j = 0; j < 4; ++j)
        acc[i][j] = __builtin_amdgcn_mfma_f32_16x16x32_bf16(af[i], bfr[j], acc[i][j], 0, 0, 0);
    __syncthreads();
  }
  const int l4 = (lane >> 4) * 4;
#pragma unroll
  for (int i = 0; i < 4; ++i)
#pragma unroll
    for (int j = 0; j < 4; ++j) {
      int col = bn + wc * 64 + j * 16 + lrow;
#pragma unroll
      for (int r = 0; r < 4; ++r) {
        int row = bm + wr * 64 + i * 16 + l4 + r;
        QKVV[(size_t)row * FOURC + col] = __float2bfloat16(acc[i][j][r]);
      }
    }
}

// ---------------- K2b: invq/invk = rsqrt(max(sumsq, eps)) ----------------
__global__ __launch_bounds__(256) void k_finalize(
    const float* __restrict__ sumsq, float* __restrict__ invq, float* __restrict__ invk) {
  int i = blockIdx.x * 256 + threadIdx.x;
  if (i < 2048) {
    invq[i] = rsqrtf(fmaxf(sumsq[i], 1e-6f));
    invk[i] = rsqrtf(fmaxf(sumsq[2048 + i], 1e-6f));
  }
}

// ---------------- K3: gram via MFMA + fused q/k sum-of-squares ----------------
__global__ __launch_bounds__(256) void k_gram_stats(
    const __hip_bfloat16* __restrict__ QKVV, float* __restrict__ G,
    float* __restrict__ sumsq) {
  __shared__ __hip_bfloat16 qT[64][40];
  __shared__ __hip_bfloat16 kT[64][40];
  __shared__ float red[32][64];
  const int bh = blockIdx.y, b = bh >> 3, h = bh & 7;
  const int nbase = blockIdx.x * 512;
  const int t = threadIdx.x, w = t >> 6, lane = t & 63;
  const int l15 = lane & 15, g = lane >> 4;
  const int srow = t >> 3, sdq = (t & 7) * 8;
  f32x4 accg[4] = {};
  float sqq[8] = {}, sqk[8] = {};
  for (int n0 = nbase; n0 < nbase + 512; n0 += 32) {
    size_t gb = (size_t)(b * SEQ + n0 + srow) * FOURC + h * HDIM + sdq;
    uint4 uq = *reinterpret_cast<const uint4*>(&QKVV[gb]);
    uint4 uk = *reinterpret_cast<const uint4*>(&QKVV[gb + CH]);
    const __hip_bfloat16* hq = reinterpret_cast<const __hip_bfloat16*>(&uq);
    const __hip_bfloat16* hk = reinterpret_cast<const __hip_bfloat16*>(&uk);
#pragma unroll
    for (int j = 0; j < 8; ++j) {
      float fq = __bfloat162float(hq[j]);
      float fk = __bfloat162float(hk[j]);
      sqq[j] = fmaf(fq, fq, sqq[j]);
      sqk[j] = fmaf(fk, fk, sqk[j]);
      qT[sdq + j][srow] = hq[j];
      kT[sdq + j][srow] = hk[j];
    }
    __syncthreads();
    bf16x8 A[4];
#pragma unroll
    for (int dt = 0; dt < 4; ++dt)
      A[dt] = *reinterpret_cast<const bf16x8*>(&qT[dt * 16 + l15][g * 8]);
    bf16x8 B = *reinterpret_cast<const bf16x8*>(&kT[w * 16 + l15][g * 8]);
#pragma unroll
    for (int dt = 0; dt < 4; ++dt)
      accg[dt] = __builtin_amdgcn_mfma_f32_16x16x32_bf16(A[dt], B, accg[dt], 0, 0, 0);
    __syncthreads();
  }
  // q sumsq reduce
#pragma unroll
  for (int j = 0; j < 8; ++j) red[srow][sdq + j] = sqq[j];
  __syncthreads();
  if (t < 64) {
    float tot = 0.f;
#pragma unroll
    for (int r = 0; r < 32; ++r) tot += red[r][t];
    atomicAdd(&sumsq[bh * 64 + t], tot);
  }
  __syncthreads();
#pragma unroll
  for (int j = 0; j < 8; ++j) red[srow][sdq + j] = sqk[j];
  __syncthreads();
  if (t < 64) {
    float tot = 0.f;
#pragma unroll
    for (int r = 0; r < 32; ++r) tot += red[r][t];
    atomicAdd(&sumsq[2048 + bh * 64 + t], tot);
  }
  float* gp = G + (size_t)bh * 4096;
#pragma unroll
  for (int dt = 0; dt < 4; ++dt)
#pragma unroll
    for (int r = 0; r < 4; ++r)
      atomicAdd(&gp[(dt * 16 + g * 4 + r) * 64 + w * 16 + l15], accg[dt][r]);
}

// ---------------- K4: channel-attention softmax ----------------
__global__ __launch_bounds__(64) void k_ca_softmax(
    float* __restrict__ G, const float* __restrict__ invq,
    const float* __restrict__ invk, const float* __restrict__ tca) {
  const int bh = blockIdx.x, h = bh & 7;
  const int d = threadIdx.x;
  float* row = G + (size_t)bh * 4096 + d * 64;
  const float s0 = invq[bh * 64 + d] * tca[h];
  float vals[64];
  float m = -3.0e38f;
#pragma unroll
  for (int e = 0; e < 64; ++e) {
    float v = row[e] * s0 * invk[bh * 64 + e];
    vals[e] = v;
    m = fmaxf(m, v);
  }
  float s = 0.f;
#pragma unroll
  for (int e = 0; e < 64; ++e) { vals[e] = __expf(vals[e] - m); s += vals[e]; }
  float r = 1.0f / s;
#pragma unroll
  for (int e = 0; e < 64; ++e) row[e] = vals[e] * r;
}

// ---------------- K6: k/v projections via MFMA ----------------
__global__ __launch_bounds__(256) void k_proj_mfma(
    const __hip_bfloat16* __restrict__ QKVV,
    const __hip_bfloat16* __restrict__ Pt,
    float* __restrict__ raw) {
  __shared__ __hip_bfloat16 cT[2][64][40];
  __shared__ __hip_bfloat16 pT[256][40];
  const int bh = blockIdx.y, b = bh >> 3, h = bh & 7;
  const int nbase = blockIdx.x * 1024;
  const int t = threadIdx.x, w = t >> 6, lane = t & 63;
  const int l15 = lane & 15, g = lane >> 4;
  const int comp = w >> 1, kh = w & 1;
  const int srow = t >> 3, sdq = (t & 7) * 8;
  f32x4 acc[4][8] = {};
  for (int n0 = nbase; n0 < nbase + 1024; n0 += 32) {
#pragma unroll
    for (int cc = 0; cc < 2; ++cc) {
      const int coff = cc ? 3 * CH : CH;
      uint4 u = *reinterpret_cast<const uint4*>(
          &QKVV[(size_t)(b * SEQ + n0 + srow) * FOURC + coff + h * HDIM + sdq]);
      const __hip_bfloat16* hp = reinterpret_cast<const __hip_bfloat16*>(&u);
#pragma unroll
      for (int j = 0; j < 8; ++j) cT[cc][sdq + j][srow] = hp[j];
    }
#pragma unroll
    for (int ps = 0; ps < 4; ++ps) {
      int k = ps * 64 + (t >> 2);
      int poff = (t & 3) * 8;
      *reinterpret_cast<uint4*>(&pT[k][poff]) =
          *reinterpret_cast<const uint4*>(&Pt[(size_t)k * SEQ + n0 + poff]);
    }
    __syncthreads();
    bf16x8 A[4], B[8];
#pragma unroll
    for (int dt = 0; dt < 4; ++dt)
      A[dt] = *reinterpret_cast<const bf16x8*>(&cT[comp][dt * 16 + l15][g * 8]);
#pragma unroll
    for (int kt = 0; kt < 8; ++kt)
      B[kt] = *reinterpret_cast<const bf16x8*>(&pT[(kh * 8 + kt) * 16 + l15][g * 8]);
#pragma unroll
    for (int dt = 0; dt < 4; ++dt)
#pragma unroll
      for (int kt = 0; kt < 8; ++kt)
        acc[dt][kt] = __builtin_amdgcn_mfma_f32_16x16x32_bf16(A[dt], B[kt], acc[dt][kt], 0, 0, 0);
    __syncthreads();
  }
  float* rp = raw + ((size_t)bh * 2 + comp) * (64 * 256);
#pragma unroll
  for (int dt = 0; dt < 4; ++dt)
#pragma unroll
    for (int kt = 0; kt < 8; ++kt)
#pragma unroll
      for (int r = 0; r < 4; ++r)
        atomicAdd(&rp[(dt * 16 + g * 4 + r) * 256 + (kh * 8 + kt) * 16 + l15],
                  acc[dt][kt][r]);
}

// ---------------- K6b: finalize projections ----------------
__global__ __launch_bounds__(256) void k_projfin(
    const float* __restrict__ raw, const float* __restrict__ invq,
    const float* __restrict__ invk, const float* __restrict__ tsa,
    __hip_bfloat16* __restrict__ kpT, __hip_bfloat16* __restrict__ vpT) {
  const int bh = blockIdx.x, h = bh & 7;
  const int t = threadIdx.x;
  __shared__ float tile[64][65];
  const float ts = tsa[h];
  const float* r0 = raw + (size_t)bh * 2 * 16384;
  for (int kc = 0; kc < 4; ++kc) {
    for (int i = t; i < 4096; i += 256) {
      int d = i >> 6, kk = i & 63;
      tile[d][kk] = r0[d * 256 + kc * 64 + kk];
    }
    __syncthreads();
    for (int i = t; i < 4096; i += 256) {
      int kk = i >> 6, d = i & 63;
      float sc = invq[bh * 64 + d] * invk[bh * 64 + d] * ts;
      kpT[(size_t)bh * 16384 + (kc * 64 + kk) * 64 + d] = __float2bfloat16(tile[d][kk] * sc);
    }
    __syncthreads();
  }
  const float* r1 = r0 + 16384;
  for (int i = t; i < 16384; i += 256)
    vpT[(size_t)bh * 16384 + i] = __float2bfloat16(r1[i]);
}

// ---------------- K7: fused output = x_ca + x_sa via MFMA ----------------
__global__ __launch_bounds__(256) void k_xout(
    const __hip_bfloat16* __restrict__ QKVV,
    const float* __restrict__ G,
    const __hip_bfloat16* __restrict__ kpT,
    const __hip_bfloat16* __restrict__ vpT,
    float* __restrict__ out) {
  __shared__ __hip_bfloat16 vs[64][264];
  __shared__ __hip_bfloat16 ps[4][16][264];
  __shared__ __hip_bfloat16 gs[64][72];
  const int bh = blockIdx.y, b = bh >> 3, h = bh & 7;
  const int nblk = blockIdx.x * 512;
  const int t = threadIdx.x, w = t >> 6, lane = t & 63;
  const int l15 = lane & 15, g = lane >> 4;
  for (int i = t; i < 2048; i += 256) {
    int d = i >> 5, k8 = (i & 31) * 8;
    *reinterpret_cast<uint4*>(&vs[d][k8]) =
        *reinterpret_cast<const uint4*>(&vpT[((size_t)bh * 64 + d) * 256 + k8]);
  }
  for (int i = t; i < 4096; i += 256)
    gs[i >> 6][i & 63] = __float2bfloat16(G[(size_t)bh * 4096 + i]);
  bf16x8 kA[2][16];
#pragma unroll
  for (int s = 0; s < 2; ++s)
#pragma unroll
    for (int f = 0; f < 16; ++f)
      kA[s][f] = *reinterpret_cast<const bf16x8*>(
          &kpT[((size_t)bh * 256 + f * 16 + l15) * 64 + s * 32 + g * 8]);
  __syncthreads();
  const __hip_bfloat16* qbase = QKVV + (size_t)b * SEQ * FOURC + h * HDIM;
  const __hip_bfloat16* vbase = qbase + 2 * CH;
  for (int c = w; c < 32; c += 4) {
    const int n0 = nblk + c * 16;
    bf16x8 qf[2], vf[2];
#pragma unroll
    for (int s = 0; s < 2; ++s) {
      qf[s] = *reinterpret_cast<const bf16x8*>(
          &qbase[(size_t)(n0 + l15) * FOURC + s * 32 + g * 8]);
      vf[s] = *reinterpret_cast<const bf16x8*>(
          &vbase[(size_t)(n0 + l15) * FOURC + s * 32 + g * 8]);
    }
    // ---- channel attention: o = attn_ca^T applied to v_ca ----
    f32x4 o[4] = {};
#pragma unroll
    for (int dt = 0; dt < 4; ++dt) {
      bf16x8 g0 = *reinterpret_cast<const bf16x8*>(&gs[dt * 16 + l15][g * 8]);
      bf16x8 g1 = *reinterpret_cast<const bf16x8*>(&gs[dt * 16 + l15][32 + g * 8]);
      o[dt] = __builtin_amdgcn_mfma_f32_16x16x32_bf16(vf[0], g0, o[dt], 0, 0, 0);
      o[dt] = __builtin_amdgcn_mfma_f32_16x16x32_bf16(vf[1], g1, o[dt], 0, 0, 0);
    }
    // ---- spatial attention: S = kpT q ----
    f32x4 acc[16] = {};
#pragma unroll
    for (int f = 0; f < 16; ++f) {
      acc[f] = __builtin_amdgcn_mfma_f32_16x16x32_bf16(kA[0][f], qf[0], acc[f], 0, 0, 0);
      acc[f] = __builtin_amdgcn_mfma_f32_16x16x32_bf16(kA[1][f], qf[1], acc[f], 0, 0, 0);
    }
    float m = -3.0e38f;
#pragma unroll
    for (int f = 0; f < 16; ++f)
#pragma unroll
      for (int r = 0; r < 4; ++r) m = fmaxf(m, acc[f][r]);
    m = fmaxf(m, __shfl_xor(m, 16));
    m = fmaxf(m, __shfl_xor(m, 32));
    float sum = 0.f;
#pragma unroll
    for (int f = 0; f < 16; ++f)
#pragma unroll
      for (int r = 0; r < 4; ++r) {
        float e = __expf(acc[f][r] - m);
        acc[f][r] = e; sum += e;
      }
    sum += __shfl_xor(sum, 16);
    sum += __shfl_xor(sum, 32);
    const float rinv = 1.0f / sum;
#pragma unroll
    for (int f = 0; f < 16; ++f) {
      uint2 pw;
      pw.x = packbf2(acc[f][0] * rinv, acc[f][1] * rinv);
      pw.y = packbf2(acc[f][2] * rinv, acc[f][3] * rinv);
      *reinterpret_cast<uint2*>(&ps[w][l15][f * 16 + g * 4]) = pw;
    }
    __builtin_amdgcn_wave_barrier();
    // ---- PV accumulates into o (free x_ca + x_sa sum) ----
#pragma unroll
    for (int s = 0; s < 8; ++s) {
      bf16x8 pa = *reinterpret_cast<const bf16x8*>(&ps[w][l15][s * 32 + g * 8]);
#pragma unroll
      for (int dt = 0; dt < 4; ++dt) {
        bf16x8 vb = *reinterpret_cast<const bf16x8*>(&vs[dt * 16 + l15][s * 32 + g * 8]);
        o[dt] = __builtin_amdgcn_mfma_f32_16x16x32_bf16(pa, vb, o[dt], 0, 0, 0);
      }
    }
#pragma unroll
    for (int dt = 0; dt < 4; ++dt)
#pragma unroll
      for (int r = 0; r < 4; ++r) {
        size_t oo = ((size_t)(b * SEQ + n0 + g * 4 + r)) * CH + h * HDIM + dt * 16 + l15;
        out[oo] = o[dt][r];
      }
    __builtin_amdgcn_wave_barrier();
  }
}

extern "C" void kernel_launch(void* const* d_in, const int* in_sizes, int n_in,
                              void* d_out, int out_size, void* d_ws, size_t ws_size,
                              hipStream_t stream) {
  const float* x   = (const float*)d_in[0];
  const float* w   = (const float*)d_in[1];
  const float* sp  = (const float*)d_in[2];
  const float* tca = (const float*)d_in[3];
  const float* tsa = (const float*)d_in[4];
  float* out = (float*)d_out;
  char* ws = (char*)d_ws;

  __hip_bfloat16* qkvv = (__hip_bfloat16*)ws;                  // 134217728
  __hip_bfloat16* wt   = (__hip_bfloat16*)(ws + 134217728);    // 2097152
  __hip_bfloat16* pt   = (__hip_bfloat16*)(ws + 136314880);    // 4194304
  __hip_bfloat16* xb   = (__hip_bfloat16*)(ws + 140509184);    // 33554432
  __hip_bfloat16* kpT  = (__hip_bfloat16*)(ws + 174063616);    // 1048576
  __hip_bfloat16* vpT  = (__hip_bfloat16*)(ws + 175112192);    // 1048576
  float* invq  = (float*)(ws + 176160768);                     // 8192
  float* invk  = (float*)(ws + 176168960);                     // 8192
  // contiguous zeroed region: G | sumsq | raw
  float* G     = (float*)(ws + 176177152);                     // 524288
  float* sumsq = (float*)(ws + 176701440);                     // 16384
  float* raw   = (float*)(ws + 176717824);                     // 4194304

  hipMemsetAsync(G, 0, 524288 + 16384 + 4194304, stream);

  hipLaunchKernelGGL(k_wt, dim3(64, 16), dim3(256), 0, stream, w, wt);
  hipLaunchKernelGGL(k_pt, dim3(256, 8), dim3(256), 0, stream, sp, pt);
  hipLaunchKernelGGL(k_xbf, dim3(8192), dim3(256), 0, stream, x, xb);
  hipLaunchKernelGGL(k_gemm_mfma, dim3(4096), dim3(256), 0, stream, xb, wt, qkvv);
  hipLaunchKernelGGL(k_gram_stats, dim3(16, 32), dim3(256), 0, stream, qkvv, G, sumsq);
  hipLaunchKernelGGL(k_proj_mfma, dim3(8, 32), dim3(256), 0, stream, qkvv, pt, raw);
  hipLaunchKernelGGL(k_finalize, dim3(8), dim3(256), 0, stream, sumsq, invq, invk);
  hipLaunchKernelGGL(k_ca_softmax, dim3(32), dim3(64), 0, stream, G, invq, invk, tca);
  hipLaunchKernelGGL(k_projfin, dim3(32), dim3(256), 0, stream, raw, invq, invk, tsa, kpT, vpT);
  hipLaunchKernelGGL(k_xout, dim3(16, 32), dim3(256), 0, stream, qkvv, G, kpT, vpT, out);
}

// Round 6
// 290.460 us; speedup vs baseline: 12.3377x; 1.0686x over previous
//
#include <hip/hip_runtime.h>
#include <hip/hip_bf16.h>

#define BATCH 4
#define SEQ   8192
#define CH    512
#define NHEAD 8
#define HDIM  64
#define KTOK  256
#define FOURC 2048

typedef __attribute__((ext_vector_type(8))) short bf16x8;
typedef __attribute__((ext_vector_type(4))) float f32x4;

#define GLOAD_LDS16(g, l)                                                      \
  __builtin_amdgcn_global_load_lds(                                            \
      (const __attribute__((address_space(1))) void*)(g),                      \
      (__attribute__((address_space(3))) void*)(l), 16, 0, 0)

__device__ __forceinline__ ushort bf16bits(float f) {
  __hip_bfloat16 b = __float2bfloat16(f);
  return *reinterpret_cast<ushort*>(&b);
}
__device__ __forceinline__ uint packbf2(float lo, float hi) {
  return (uint)bf16bits(lo) | ((uint)bf16bits(hi) << 16);
}

// ---------------- K0: W [512][2048] fp32 -> Wt [2048][512] bf16 ----------------
__global__ __launch_bounds__(256) void k_wt(
    const float* __restrict__ W, __hip_bfloat16* __restrict__ Wt) {
  __shared__ float tile[32][33];
  const int bx = blockIdx.x * 32;
  const int by = blockIdx.y * 32;
  const int t = threadIdx.x;
  const int r = t >> 5, c = t & 31;
#pragma unroll
  for (int it = 0; it < 4; ++it)
    tile[r + it * 8][c] = W[(size_t)(by + r + it * 8) * FOURC + bx + c];
  __syncthreads();
#pragma unroll
  for (int it = 0; it < 4; ++it) {
    int n = r + it * 8;
    Wt[(size_t)(bx + n) * CH + by + c] = __float2bfloat16(tile[c][n]);
  }
}

// ---------------- K0b: P [8192][256] fp32 -> Pt [256][8192] bf16 ----------------
__global__ __launch_bounds__(256) void k_pt(
    const float* __restrict__ P, __hip_bfloat16* __restrict__ Pt) {
  __shared__ float tile[32][33];
  const int n0 = blockIdx.x * 32, k0 = blockIdx.y * 32;
  const int t = threadIdx.x, r = t >> 5, c = t & 31;
#pragma unroll
  for (int i = 0; i < 4; ++i)
    tile[r + i * 8][c] = P[(size_t)(n0 + r + i * 8) * KTOK + k0 + c];
  __syncthreads();
#pragma unroll
  for (int i = 0; i < 4; ++i)
    Pt[(size_t)(k0 + r + i * 8) * SEQ + n0 + c] = __float2bfloat16(tile[c][r + i * 8]);
}

// ---------------- K0c: X fp32 -> Xb bf16 (flat stream) ----------------
__global__ __launch_bounds__(256) void k_xbf(
    const float* __restrict__ X, __hip_bfloat16* __restrict__ Xb) {
  size_t i = ((size_t)blockIdx.x * 256 + threadIdx.x) * 8;
  float4 a = *reinterpret_cast<const float4*>(&X[i]);
  float4 b = *reinterpret_cast<const float4*>(&X[i + 4]);
  ushort tmp[8];
  tmp[0] = bf16bits(a.x); tmp[1] = bf16bits(a.y);
  tmp[2] = bf16bits(a.z); tmp[3] = bf16bits(a.w);
  tmp[4] = bf16bits(b.x); tmp[5] = bf16bits(b.y);
  tmp[6] = bf16bits(b.z); tmp[7] = bf16bits(b.w);
  *reinterpret_cast<uint4*>(&Xb[i]) = *reinterpret_cast<const uint4*>(tmp);
}

// ---------------- K1: qkvv = Xb @ Wt, bf16 MFMA, gload_lds + XOR swizzle ----------------
// LDS slot permutation within each 64B row: s_lin = s_data ^ ((row>>1)&3).
// Write: linear dest, source k-offset pre-swizzled. Read: slot (g ^ f(row)).
__global__ __launch_bounds__(256) void k_gemm_mfma(
    const __hip_bfloat16* __restrict__ Xb, const __hip_bfloat16* __restrict__ Wt,
    __hip_bfloat16* __restrict__ QKVV) {
  __shared__ __align__(16) __hip_bfloat16 As[128 * 32];  // [m][k], swizzled slots
  __shared__ __align__(16) __hip_bfloat16 Bs[128 * 32];  // [n][k], swizzled slots
  const int t = threadIdx.x;
  const int wid = t >> 6, lane = t & 63;
  const int bid = blockIdx.x;
  const int xcd = bid & 7;
  const int l = bid >> 3;
  const int bm = (xcd * 32 + (l >> 4)) * 128;
  const int bn = (l & 15) * 128;
  const int wr = wid >> 1, wc = wid & 1;
  const int lrow = lane & 15;
  // read slot: data slot g = lane>>4, f(row) = ((lane&15)>>1)&3 (rows differ by x16)
  const int lk = (((lane >> 4) ^ ((lrow >> 1) & 3))) * 8;
  const int srow = lane >> 2;
  // write: lane's linear slot = lane&3; f(row)=(lane>>3)&3 -> load data slot (lin^f)
  const int sk8 = (((lane & 3) ^ ((lane >> 3) & 3))) * 8;
  f32x4 acc[4][4] = {};
  for (int k0 = 0; k0 < CH; k0 += 32) {
#pragma unroll
    for (int i = 0; i < 2; ++i) {
      const int c = wid * 2 + i;
      GLOAD_LDS16(&Xb[(size_t)(bm + c * 16 + srow) * CH + k0 + sk8], &As[c * 512]);
      GLOAD_LDS16(&Wt[(size_t)(bn + c * 16 + srow) * CH + k0 + sk8], &Bs[c * 512]);
    }
    __syncthreads();
    bf16x8 af[4], bfr[4];
#pragma unroll
    for (int i = 0; i < 4; ++i)
      af[i] = *reinterpret_cast<const bf16x8*>(&As[(wr * 64 + i * 16 + lrow) * 32 + lk]);
#pragma unroll
    for (int j = 0; j < 4; ++j)
      bfr[j] = *reinterpret_cast<const bf16x8*>(&Bs[(wc * 64 + j * 16 + lrow) * 32 + lk]);
#pragma unroll
    for (int i = 0; i < 4; ++i)
#pragma unroll
      for (int j = 0; j < 4; ++j)
        acc[i][j] = __builtin_amdgcn_mfma_f32_16x16x32_bf16(af[i], bfr[j], acc[i][j], 0, 0, 0);
    __syncthreads();
  }
  const int l4 = (lane >> 4) * 4;
#pragma unroll
  for (int i = 0; i < 4; ++i)
#pragma unroll
    for (int j = 0; j < 4; ++j) {
      int col = bn + wc * 64 + j * 16 + lrow;
#pragma unroll
      for (int r = 0; r < 4; ++r) {
        int row = bm + wr * 64 + i * 16 + l4 + r;
        QKVV[(size_t)row * FOURC + col] = __float2bfloat16(acc[i][j][r]);
      }
    }
}

// ---------------- K2b: invq/invk = rsqrt(max(sumsq, eps)) ----------------
__global__ __launch_bounds__(256) void k_finalize(
    const float* __restrict__ sumsq, float* __restrict__ invq, float* __restrict__ invk) {
  int i = blockIdx.x * 256 + threadIdx.x;
  if (i < 2048) {
    invq[i] = rsqrtf(fmaxf(sumsq[i], 1e-6f));
    invk[i] = rsqrtf(fmaxf(sumsq[2048 + i], 1e-6f));
  }
}

// ---------------- K3: fused gram + sumsq + k/v projections (one pass over q,k,v_sa) ----------------
__global__ __launch_bounds__(256) void k_qkstats(
    const __hip_bfloat16* __restrict__ QKVV,
    const __hip_bfloat16* __restrict__ Pt,
    float* __restrict__ G, float* __restrict__ sumsq, float* __restrict__ raw) {
  __shared__ __hip_bfloat16 qT[64][40];
  __shared__ __hip_bfloat16 kT[64][40];
  __shared__ __hip_bfloat16 vT[64][40];
  __shared__ __hip_bfloat16 pT[256][40];
  __shared__ float red[32][64];
  const int bh = blockIdx.y, b = bh >> 3, h = bh & 7;
  const int nbase = blockIdx.x * 1024;
  const int t = threadIdx.x, w = t >> 6, lane = t & 63;
  const int l15 = lane & 15, g = lane >> 4;
  const int comp = w >> 1, kh = w & 1;
  const int srow = t >> 3, sdq = (t & 7) * 8;
  f32x4 acc[4][8] = {};   // proj quadrant
  f32x4 accg[4] = {};     // gram e-quarter
  float sqq[8] = {}, sqk[8] = {};
  for (int n0 = nbase; n0 < nbase + 1024; n0 += 32) {
    size_t gb = (size_t)(b * SEQ + n0 + srow) * FOURC + h * HDIM + sdq;
    uint4 uq = *reinterpret_cast<const uint4*>(&QKVV[gb]);
    uint4 uk = *reinterpret_cast<const uint4*>(&QKVV[gb + CH]);
    uint4 uv = *reinterpret_cast<const uint4*>(&QKVV[gb + 3 * CH]);
    const __hip_bfloat16* hq = reinterpret_cast<const __hip_bfloat16*>(&uq);
    const __hip_bfloat16* hk = reinterpret_cast<const __hip_bfloat16*>(&uk);
    const __hip_bfloat16* hv = reinterpret_cast<const __hip_bfloat16*>(&uv);
#pragma unroll
    for (int j = 0; j < 8; ++j) {
      float fq = __bfloat162float(hq[j]);
      float fk = __bfloat162float(hk[j]);
      sqq[j] = fmaf(fq, fq, sqq[j]);
      sqk[j] = fmaf(fk, fk, sqk[j]);
      qT[sdq + j][srow] = hq[j];
      kT[sdq + j][srow] = hk[j];
      vT[sdq + j][srow] = hv[j];
    }
#pragma unroll
    for (int ps = 0; ps < 4; ++ps) {
      int k = ps * 64 + (t >> 2);
      int poff = (t & 3) * 8;
      *reinterpret_cast<uint4*>(&pT[k][poff]) =
          *reinterpret_cast<const uint4*>(&Pt[(size_t)k * SEQ + n0 + poff]);
    }
    __syncthreads();
    // gram: G[d][e] partial, wave owns e-quarter w*16
    {
      bf16x8 Aq[4];
#pragma unroll
      for (int dt = 0; dt < 4; ++dt)
        Aq[dt] = *reinterpret_cast<const bf16x8*>(&qT[dt * 16 + l15][g * 8]);
      bf16x8 Bk = *reinterpret_cast<const bf16x8*>(&kT[w * 16 + l15][g * 8]);
#pragma unroll
      for (int dt = 0; dt < 4; ++dt)
        accg[dt] = __builtin_amdgcn_mfma_f32_16x16x32_bf16(Aq[dt], Bk, accg[dt], 0, 0, 0);
    }
    // proj: comp 0 = k -> kproj, 1 = v_sa -> vproj; wave owns k-half kh
    {
      bf16x8 A[4], B[8];
#pragma unroll
      for (int dt = 0; dt < 4; ++dt)
        A[dt] = comp ? *reinterpret_cast<const bf16x8*>(&vT[dt * 16 + l15][g * 8])
                     : *reinterpret_cast<const bf16x8*>(&kT[dt * 16 + l15][g * 8]);
#pragma unroll
      for (int kt = 0; kt < 8; ++kt)
        B[kt] = *reinterpret_cast<const bf16x8*>(&pT[(kh * 8 + kt) * 16 + l15][g * 8]);
#pragma unroll
      for (int dt = 0; dt < 4; ++dt)
#pragma unroll
        for (int kt = 0; kt < 8; ++kt)
          acc[dt][kt] = __builtin_amdgcn_mfma_f32_16x16x32_bf16(A[dt], B[kt], acc[dt][kt], 0, 0, 0);
    }
    __syncthreads();
  }
  // sumsq reductions
#pragma unroll
  for (int j = 0; j < 8; ++j) red[srow][sdq + j] = sqq[j];
  __syncthreads();
  if (t < 64) {
    float tot = 0.f;
#pragma unroll
    for (int r = 0; r < 32; ++r) tot += red[r][t];
    atomicAdd(&sumsq[bh * 64 + t], tot);
  }
  __syncthreads();
#pragma unroll
  for (int j = 0; j < 8; ++j) red[srow][sdq + j] = sqk[j];
  __syncthreads();
  if (t < 64) {
    float tot = 0.f;
#pragma unroll
    for (int r = 0; r < 32; ++r) tot += red[r][t];
    atomicAdd(&sumsq[2048 + bh * 64 + t], tot);
  }
  // gram partials
  float* gp = G + (size_t)bh * 4096;
#pragma unroll
  for (int dt = 0; dt < 4; ++dt)
#pragma unroll
    for (int r = 0; r < 4; ++r)
      atomicAdd(&gp[(dt * 16 + g * 4 + r) * 64 + w * 16 + l15], accg[dt][r]);
  // proj partials
  float* rp = raw + ((size_t)bh * 2 + comp) * (64 * 256);
#pragma unroll
  for (int dt = 0; dt < 4; ++dt)
#pragma unroll
    for (int kt = 0; kt < 8; ++kt)
#pragma unroll
      for (int r = 0; r < 4; ++r)
        atomicAdd(&rp[(dt * 16 + g * 4 + r) * 256 + (kh * 8 + kt) * 16 + l15],
                  acc[dt][kt][r]);
}

// ---------------- K4: channel-attention softmax ----------------
__global__ __launch_bounds__(64) void k_ca_softmax(
    float* __restrict__ G, const float* __restrict__ invq,
    const float* __restrict__ invk, const float* __restrict__ tca) {
  const int bh = blockIdx.x, h = bh & 7;
  const int d = threadIdx.x;
  float* row = G + (size_t)bh * 4096 + d * 64;
  const float s0 = invq[bh * 64 + d] * tca[h];
  float vals[64];
  float m = -3.0e38f;
#pragma unroll
  for (int e = 0; e < 64; ++e) {
    float v = row[e] * s0 * invk[bh * 64 + e];
    vals[e] = v;
    m = fmaxf(m, v);
  }
  float s = 0.f;
#pragma unroll
  for (int e = 0; e < 64; ++e) { vals[e] = __expf(vals[e] - m); s += vals[e]; }
  float r = 1.0f / s;
#pragma unroll
  for (int e = 0; e < 64; ++e) row[e] = vals[e] * r;
}

// ---------------- K6b: finalize projections ----------------
__global__ __launch_bounds__(256) void k_projfin(
    const float* __restrict__ raw, const float* __restrict__ invq,
    const float* __restrict__ invk, const float* __restrict__ tsa,
    __hip_bfloat16* __restrict__ kpT, __hip_bfloat16* __restrict__ vpT) {
  const int bh = blockIdx.x, h = bh & 7;
  const int t = threadIdx.x;
  __shared__ float tile[64][65];
  const float ts = tsa[h];
  const float* r0 = raw + (size_t)bh * 2 * 16384;
  for (int kc = 0; kc < 4; ++kc) {
    for (int i = t; i < 4096; i += 256) {
      int d = i >> 6, kk = i & 63;
      tile[d][kk] = r0[d * 256 + kc * 64 + kk];
    }
    __syncthreads();
    for (int i = t; i < 4096; i += 256) {
      int kk = i >> 6, d = i & 63;
      float sc = invq[bh * 64 + d] * invk[bh * 64 + d] * ts;
      kpT[(size_t)bh * 16384 + (kc * 64 + kk) * 64 + d] = __float2bfloat16(tile[d][kk] * sc);
    }
    __syncthreads();
  }
  const float* r1 = r0 + 16384;
  for (int i = t; i < 16384; i += 256)
    vpT[(size_t)bh * 16384 + i] = __float2bfloat16(r1[i]);
}

// ---------------- K7: fused output = x_ca + x_sa via MFMA ----------------
__global__ __launch_bounds__(256) void k_xout(
    const __hip_bfloat16* __restrict__ QKVV,
    const float* __restrict__ G,
    const __hip_bfloat16* __restrict__ kpT,
    const __hip_bfloat16* __restrict__ vpT,
    float* __restrict__ out) {
  __shared__ __hip_bfloat16 vs[64][264];
  __shared__ __hip_bfloat16 ps[4][16][264];
  __shared__ __hip_bfloat16 gs[64][72];
  const int bh = blockIdx.y, b = bh >> 3, h = bh & 7;
  const int nblk = blockIdx.x * 512;
  const int t = threadIdx.x, w = t >> 6, lane = t & 63;
  const int l15 = lane & 15, g = lane >> 4;
  for (int i = t; i < 2048; i += 256) {
    int d = i >> 5, k8 = (i & 31) * 8;
    *reinterpret_cast<uint4*>(&vs[d][k8]) =
        *reinterpret_cast<const uint4*>(&vpT[((size_t)bh * 64 + d) * 256 + k8]);
  }
  for (int i = t; i < 4096; i += 256)
    gs[i >> 6][i & 63] = __float2bfloat16(G[(size_t)bh * 4096 + i]);
  bf16x8 kA[2][16];
#pragma unroll
  for (int s = 0; s < 2; ++s)
#pragma unroll
    for (int f = 0; f < 16; ++f)
      kA[s][f] = *reinterpret_cast<const bf16x8*>(
          &kpT[((size_t)bh * 256 + f * 16 + l15) * 64 + s * 32 + g * 8]);
  __syncthreads();
  const __hip_bfloat16* qbase = QKVV + (size_t)b * SEQ * FOURC + h * HDIM;
  const __hip_bfloat16* vbase = qbase + 2 * CH;
  for (int c = w; c < 32; c += 4) {
    const int n0 = nblk + c * 16;
    bf16x8 qf[2], vf[2];
#pragma unroll
    for (int s = 0; s < 2; ++s) {
      qf[s] = *reinterpret_cast<const bf16x8*>(
          &qbase[(size_t)(n0 + l15) * FOURC + s * 32 + g * 8]);
      vf[s] = *reinterpret_cast<const bf16x8*>(
          &vbase[(size_t)(n0 + l15) * FOURC + s * 32 + g * 8]);
    }
    f32x4 o[4] = {};
#pragma unroll
    for (int dt = 0; dt < 4; ++dt) {
      bf16x8 g0 = *reinterpret_cast<const bf16x8*>(&gs[dt * 16 + l15][g * 8]);
      bf16x8 g1 = *reinterpret_cast<const bf16x8*>(&gs[dt * 16 + l15][32 + g * 8]);
      o[dt] = __builtin_amdgcn_mfma_f32_16x16x32_bf16(vf[0], g0, o[dt], 0, 0, 0);
      o[dt] = __builtin_amdgcn_mfma_f32_16x16x32_bf16(vf[1], g1, o[dt], 0, 0, 0);
    }
    f32x4 acc[16] = {};
#pragma unroll
    for (int f = 0; f < 16; ++f) {
      acc[f] = __builtin_amdgcn_mfma_f32_16x16x32_bf16(kA[0][f], qf[0], acc[f], 0, 0, 0);
      acc[f] = __builtin_amdgcn_mfma_f32_16x16x32_bf16(kA[1][f], qf[1], acc[f], 0, 0, 0);
    }
    float m = -3.0e38f;
#pragma unroll
    for (int f = 0; f < 16; ++f)
#pragma unroll
      for (int r = 0; r < 4; ++r) m = fmaxf(m, acc[f][r]);
    m = fmaxf(m, __shfl_xor(m, 16));
    m = fmaxf(m, __shfl_xor(m, 32));
    float sum = 0.f;
#pragma unroll
    for (int f = 0; f < 16; ++f)
#pragma unroll
      for (int r = 0; r < 4; ++r) {
        float e = __expf(acc[f][r] - m);
        acc[f][r] = e; sum += e;
      }
    sum += __shfl_xor(sum, 16);
    sum += __shfl_xor(sum, 32);
    const float rinv = 1.0f / sum;
#pragma unroll
    for (int f = 0; f < 16; ++f) {
      uint2 pw;
      pw.x = packbf2(acc[f][0] * rinv, acc[f][1] * rinv);
      pw.y = packbf2(acc[f][2] * rinv, acc[f][3] * rinv);
      *reinterpret_cast<uint2*>(&ps[w][l15][f * 16 + g * 4]) = pw;
    }
    __builtin_amdgcn_wave_barrier();
#pragma unroll
    for (int s = 0; s < 8; ++s) {
      bf16x8 pa = *reinterpret_cast<const bf16x8*>(&ps[w][l15][s * 32 + g * 8]);
#pragma unroll
      for (int dt = 0; dt < 4; ++dt) {
        bf16x8 vb = *reinterpret_cast<const bf16x8*>(&vs[dt * 16 + l15][s * 32 + g * 8]);
        o[dt] = __builtin_amdgcn_mfma_f32_16x16x32_bf16(pa, vb, o[dt], 0, 0, 0);
      }
    }
#pragma unroll
    for (int dt = 0; dt < 4; ++dt)
#pragma unroll
      for (int r = 0; r < 4; ++r) {
        size_t oo = ((size_t)(b * SEQ + n0 + g * 4 + r)) * CH + h * HDIM + dt * 16 + l15;
        out[oo] = o[dt][r];
      }
    __builtin_amdgcn_wave_barrier();
  }
}

extern "C" void kernel_launch(void* const* d_in, const int* in_sizes, int n_in,
                              void* d_out, int out_size, void* d_ws, size_t ws_size,
                              hipStream_t stream) {
  const float* x   = (const float*)d_in[0];
  const float* w   = (const float*)d_in[1];
  const float* sp  = (const float*)d_in[2];
  const float* tca = (const float*)d_in[3];
  const float* tsa = (const float*)d_in[4];
  float* out = (float*)d_out;
  char* ws = (char*)d_ws;

  __hip_bfloat16* qkvv = (__hip_bfloat16*)ws;                  // 134217728
  __hip_bfloat16* wt   = (__hip_bfloat16*)(ws + 134217728);    // 2097152
  __hip_bfloat16* pt   = (__hip_bfloat16*)(ws + 136314880);    // 4194304
  __hip_bfloat16* xb   = (__hip_bfloat16*)(ws + 140509184);    // 33554432
  __hip_bfloat16* kpT  = (__hip_bfloat16*)(ws + 174063616);    // 1048576
  __hip_bfloat16* vpT  = (__hip_bfloat16*)(ws + 175112192);    // 1048576
  float* invq  = (float*)(ws + 176160768);                     // 8192
  float* invk  = (float*)(ws + 176168960);                     // 8192
  // contiguous zeroed region: G | sumsq | raw
  float* G     = (float*)(ws + 176177152);                     // 524288
  float* sumsq = (float*)(ws + 176701440);                     // 16384
  float* raw   = (float*)(ws + 176717824);                     // 4194304

  hipMemsetAsync(G, 0, 524288 + 16384 + 4194304, stream);

  hipLaunchKernelGGL(k_wt, dim3(64, 16), dim3(256), 0, stream, w, wt);
  hipLaunchKernelGGL(k_pt, dim3(256, 8), dim3(256), 0, stream, sp, pt);
  hipLaunchKernelGGL(k_xbf, dim3(8192), dim3(256), 0, stream, x, xb);
  hipLaunchKernelGGL(k_gemm_mfma, dim3(4096), dim3(256), 0, stream, xb, wt, qkvv);
  hipLaunchKernelGGL(k_qkstats, dim3(8, 32), dim3(256), 0, stream, qkvv, pt, G, sumsq, raw);
  hipLaunchKernelGGL(k_finalize, dim3(8), dim3(256), 0, stream, sumsq, invq, invk);
  hipLaunchKernelGGL(k_ca_softmax, dim3(32), dim3(64), 0, stream, G, invq, invk, tca);
  hipLaunchKernelGGL(k_projfin, dim3(32), dim3(256), 0, stream, raw, invq, invk, tsa, kpT, vpT);
  hipLaunchKernelGGL(k_xout, dim3(16, 32), dim3(256), 0, stream, qkvv, G, kpT, vpT, out);
}

// Round 7
// 287.241 us; speedup vs baseline: 12.4760x; 1.0112x over previous
//
#include <hip/hip_runtime.h>
#include <hip/hip_bf16.h>

#define BATCH 4
#define SEQ   8192
#define CH    512
#define NHEAD 8
#define HDIM  64
#define KTOK  256
#define FOURC 2048

typedef __attribute__((ext_vector_type(8))) short bf16x8;
typedef __attribute__((ext_vector_type(4))) float f32x4;

#define GLOAD_LDS16(g, l)                                                      \
  __builtin_amdgcn_global_load_lds(                                            \
      (const __attribute__((address_space(1))) void*)(g),                      \
      (__attribute__((address_space(3))) void*)(l), 16, 0, 0)

__device__ __forceinline__ ushort bf16bits(float f) {
  __hip_bfloat16 b = __float2bfloat16(f);
  return *reinterpret_cast<ushort*>(&b);
}
__device__ __forceinline__ uint packbf2(float lo, float hi) {
  return (uint)bf16bits(lo) | ((uint)bf16bits(hi) << 16);
}

// ---------------- K0: W [512][2048] fp32 -> Wt [2048][512] bf16 ----------------
__global__ __launch_bounds__(256) void k_wt(
    const float* __restrict__ W, __hip_bfloat16* __restrict__ Wt) {
  __shared__ float tile[32][33];
  const int bx = blockIdx.x * 32;
  const int by = blockIdx.y * 32;
  const int t = threadIdx.x;
  const int r = t >> 5, c = t & 31;
#pragma unroll
  for (int it = 0; it < 4; ++it)
    tile[r + it * 8][c] = W[(size_t)(by + r + it * 8) * FOURC + bx + c];
  __syncthreads();
#pragma unroll
  for (int it = 0; it < 4; ++it) {
    int n = r + it * 8;
    Wt[(size_t)(bx + n) * CH + by + c] = __float2bfloat16(tile[c][n]);
  }
}

// ---------------- K0b: P [8192][256] fp32 -> Pt [256][8192] bf16 ----------------
__global__ __launch_bounds__(256) void k_pt(
    const float* __restrict__ P, __hip_bfloat16* __restrict__ Pt) {
  __shared__ float tile[32][33];
  const int n0 = blockIdx.x * 32, k0 = blockIdx.y * 32;
  const int t = threadIdx.x, r = t >> 5, c = t & 31;
#pragma unroll
  for (int i = 0; i < 4; ++i)
    tile[r + i * 8][c] = P[(size_t)(n0 + r + i * 8) * KTOK + k0 + c];
  __syncthreads();
#pragma unroll
  for (int i = 0; i < 4; ++i)
    Pt[(size_t)(k0 + r + i * 8) * SEQ + n0 + c] = __float2bfloat16(tile[c][r + i * 8]);
}

// ---------------- K0c: X fp32 -> Xb bf16 (flat stream) ----------------
__global__ __launch_bounds__(256) void k_xbf(
    const float* __restrict__ X, __hip_bfloat16* __restrict__ Xb) {
  size_t i = ((size_t)blockIdx.x * 256 + threadIdx.x) * 8;
  float4 a = *reinterpret_cast<const float4*>(&X[i]);
  float4 b = *reinterpret_cast<const float4*>(&X[i + 4]);
  ushort tmp[8];
  tmp[0] = bf16bits(a.x); tmp[1] = bf16bits(a.y);
  tmp[2] = bf16bits(a.z); tmp[3] = bf16bits(a.w);
  tmp[4] = bf16bits(b.x); tmp[5] = bf16bits(b.y);
  tmp[6] = bf16bits(b.z); tmp[7] = bf16bits(b.w);
  *reinterpret_cast<uint4*>(&Xb[i]) = *reinterpret_cast<const uint4*>(tmp);
}

// ---------------- K1: qkvv = Xb @ Wt, bf16 MFMA, counted-vmcnt double buffer ----------------
__global__ __launch_bounds__(256) void k_gemm_mfma(
    const __hip_bfloat16* __restrict__ Xb, const __hip_bfloat16* __restrict__ Wt,
    __hip_bfloat16* __restrict__ QKVV) {
  __shared__ __align__(16) __hip_bfloat16 As[2][128 * 32];
  __shared__ __align__(16) __hip_bfloat16 Bs[2][128 * 32];
  const int t = threadIdx.x;
  const int wid = t >> 6, lane = t & 63;
  const int bid = blockIdx.x;
  const int xcd = bid & 7;
  const int l = bid >> 3;
  const int bm = (xcd * 32 + (l >> 4)) * 128;
  const int bn = (l & 15) * 128;
  const int wr = wid >> 1, wc = wid & 1;
  const int lrow = lane & 15;
  const int lk = (((lane >> 4) ^ ((lrow >> 1) & 3))) * 8;
  const int srow = lane >> 2;
  const int sk8 = (((lane & 3) ^ ((lane >> 3) & 3))) * 8;
  const int c0 = wid * 2, c1 = wid * 2 + 1;
  f32x4 acc[4][4] = {};

#define STAGE(bufi, kk)                                                         \
  do {                                                                          \
    GLOAD_LDS16(&Xb[(size_t)(bm + c0 * 16 + srow) * CH + (kk) + sk8],           \
                &As[bufi][c0 * 512]);                                           \
    GLOAD_LDS16(&Wt[(size_t)(bn + c0 * 16 + srow) * CH + (kk) + sk8],           \
                &Bs[bufi][c0 * 512]);                                           \
    GLOAD_LDS16(&Xb[(size_t)(bm + c1 * 16 + srow) * CH + (kk) + sk8],           \
                &As[bufi][c1 * 512]);                                           \
    GLOAD_LDS16(&Wt[(size_t)(bn + c1 * 16 + srow) * CH + (kk) + sk8],           \
                &Bs[bufi][c1 * 512]);                                           \
  } while (0)

  STAGE(0, 0);
#pragma unroll 4
  for (int kt = 0; kt < 16; ++kt) {
    const int cur = kt & 1;
    if (kt < 15) {
      STAGE(cur ^ 1, (kt + 1) * 32);
      asm volatile("s_waitcnt vmcnt(4)" ::: "memory");
    } else {
      asm volatile("s_waitcnt vmcnt(0)" ::: "memory");
    }
    __builtin_amdgcn_s_barrier();
    bf16x8 af[4], bfr[4];
#pragma unroll
    for (int i = 0; i < 4; ++i)
      af[i] = *reinterpret_cast<const bf16x8*>(&As[cur][(wr * 64 + i * 16 + lrow) * 32 + lk]);
#pragma unroll
    for (int j = 0; j < 4; ++j)
      bfr[j] = *reinterpret_cast<const bf16x8*>(&Bs[cur][(wc * 64 + j * 16 + lrow) * 32 + lk]);
#pragma unroll
    for (int i = 0; i < 4; ++i)
#pragma unroll
      for (int j = 0; j < 4; ++j)
        acc[i][j] = __builtin_amdgcn_mfma_f32_16x16x32_bf16(af[i], bfr[j], acc[i][j], 0, 0, 0);
    asm volatile("s_waitcnt lgkmcnt(0)" ::: "memory");
    __builtin_amdgcn_s_barrier();
  }
#undef STAGE
  const int l4 = (lane >> 4) * 4;
#pragma unroll
  for (int i = 0; i < 4; ++i)
#pragma unroll
    for (int j = 0; j < 4; ++j) {
      int col = bn + wc * 64 + j * 16 + lrow;
#pragma unroll
      for (int r = 0; r < 4; ++r) {
        int row = bm + wr * 64 + i * 16 + l4 + r;
        QKVV[(size_t)row * FOURC + col] = __float2bfloat16(acc[i][j][r]);
      }
    }
}

// ---------------- K3: fused gram + sumsq + k/v projections (pipelined) ----------------
__global__ __launch_bounds__(256) void k_qkstats(
    const __hip_bfloat16* __restrict__ QKVV,
    const __hip_bfloat16* __restrict__ Pt,
    float* __restrict__ G, float* __restrict__ sumsq, float* __restrict__ raw) {
  __shared__ __hip_bfloat16 qT[64][40];
  __shared__ __hip_bfloat16 kT[64][40];
  __shared__ __hip_bfloat16 vT[64][40];
  __shared__ __hip_bfloat16 pT[256][40];
  __shared__ float red[32][64];
  const int bh = blockIdx.y, b = bh >> 3, h = bh & 7;
  const int nbase = blockIdx.x * 1024;
  const int t = threadIdx.x, w = t >> 6, lane = t & 63;
  const int l15 = lane & 15, g = lane >> 4;
  const int comp = w >> 1, kh = w & 1;
  const int srow = t >> 3, sdq = (t & 7) * 8;
  const int prow = t >> 2, poff = (t & 3) * 8;
  f32x4 acc[4][8] = {};
  f32x4 accg[4] = {};
  float sqq[8] = {}, sqk[8] = {};
  uint4 uq, uk, uv, up0, up1, up2, up3;
  // prologue load chunk 0
  {
    size_t gb = (size_t)(b * SEQ + nbase + srow) * FOURC + h * HDIM + sdq;
    uq = *reinterpret_cast<const uint4*>(&QKVV[gb]);
    uk = *reinterpret_cast<const uint4*>(&QKVV[gb + CH]);
    uv = *reinterpret_cast<const uint4*>(&QKVV[gb + 3 * CH]);
    up0 = *reinterpret_cast<const uint4*>(&Pt[(size_t)(0 * 64 + prow) * SEQ + nbase + poff]);
    up1 = *reinterpret_cast<const uint4*>(&Pt[(size_t)(1 * 64 + prow) * SEQ + nbase + poff]);
    up2 = *reinterpret_cast<const uint4*>(&Pt[(size_t)(2 * 64 + prow) * SEQ + nbase + poff]);
    up3 = *reinterpret_cast<const uint4*>(&Pt[(size_t)(3 * 64 + prow) * SEQ + nbase + poff]);
  }
  for (int it = 0; it < 32; ++it) {
    // stage regs -> LDS (+ sumsq accumulation)
    {
      const __hip_bfloat16* hq = reinterpret_cast<const __hip_bfloat16*>(&uq);
      const __hip_bfloat16* hk = reinterpret_cast<const __hip_bfloat16*>(&uk);
      const __hip_bfloat16* hv = reinterpret_cast<const __hip_bfloat16*>(&uv);
#pragma unroll
      for (int j = 0; j < 8; ++j) {
        float fq = __bfloat162float(hq[j]);
        float fk = __bfloat162float(hk[j]);
        sqq[j] = fmaf(fq, fq, sqq[j]);
        sqk[j] = fmaf(fk, fk, sqk[j]);
        qT[sdq + j][srow] = hq[j];
        kT[sdq + j][srow] = hk[j];
        vT[sdq + j][srow] = hv[j];
      }
      *reinterpret_cast<uint4*>(&pT[0 * 64 + prow][poff]) = up0;
      *reinterpret_cast<uint4*>(&pT[1 * 64 + prow][poff]) = up1;
      *reinterpret_cast<uint4*>(&pT[2 * 64 + prow][poff]) = up2;
      *reinterpret_cast<uint4*>(&pT[3 * 64 + prow][poff]) = up3;
    }
    // issue next chunk loads (overlap with MFMA below)
    if (it < 31) {
      const int nn = nbase + (it + 1) * 32;
      size_t gb = (size_t)(b * SEQ + nn + srow) * FOURC + h * HDIM + sdq;
      uq = *reinterpret_cast<const uint4*>(&QKVV[gb]);
      uk = *reinterpret_cast<const uint4*>(&QKVV[gb + CH]);
      uv = *reinterpret_cast<const uint4*>(&QKVV[gb + 3 * CH]);
      up0 = *reinterpret_cast<const uint4*>(&Pt[(size_t)(0 * 64 + prow) * SEQ + nn + poff]);
      up1 = *reinterpret_cast<const uint4*>(&Pt[(size_t)(1 * 64 + prow) * SEQ + nn + poff]);
      up2 = *reinterpret_cast<const uint4*>(&Pt[(size_t)(2 * 64 + prow) * SEQ + nn + poff]);
      up3 = *reinterpret_cast<const uint4*>(&Pt[(size_t)(3 * 64 + prow) * SEQ + nn + poff]);
    }
    __syncthreads();
    // gram
    {
      bf16x8 Aq[4];
#pragma unroll
      for (int dt = 0; dt < 4; ++dt)
        Aq[dt] = *reinterpret_cast<const bf16x8*>(&qT[dt * 16 + l15][g * 8]);
      bf16x8 Bk = *reinterpret_cast<const bf16x8*>(&kT[w * 16 + l15][g * 8]);
#pragma unroll
      for (int dt = 0; dt < 4; ++dt)
        accg[dt] = __builtin_amdgcn_mfma_f32_16x16x32_bf16(Aq[dt], Bk, accg[dt], 0, 0, 0);
    }
    // proj
    {
      bf16x8 A[4], B[8];
#pragma unroll
      for (int dt = 0; dt < 4; ++dt)
        A[dt] = comp ? *reinterpret_cast<const bf16x8*>(&vT[dt * 16 + l15][g * 8])
                     : *reinterpret_cast<const bf16x8*>(&kT[dt * 16 + l15][g * 8]);
#pragma unroll
      for (int kt = 0; kt < 8; ++kt)
        B[kt] = *reinterpret_cast<const bf16x8*>(&pT[(kh * 8 + kt) * 16 + l15][g * 8]);
#pragma unroll
      for (int dt = 0; dt < 4; ++dt)
#pragma unroll
        for (int kt = 0; kt < 8; ++kt)
          acc[dt][kt] = __builtin_amdgcn_mfma_f32_16x16x32_bf16(A[dt], B[kt], acc[dt][kt], 0, 0, 0);
    }
    __syncthreads();
  }
  // sumsq reductions
#pragma unroll
  for (int j = 0; j < 8; ++j) red[srow][sdq + j] = sqq[j];
  __syncthreads();
  if (t < 64) {
    float tot = 0.f;
#pragma unroll
    for (int r = 0; r < 32; ++r) tot += red[r][t];
    atomicAdd(&sumsq[bh * 64 + t], tot);
  }
  __syncthreads();
#pragma unroll
  for (int j = 0; j < 8; ++j) red[srow][sdq + j] = sqk[j];
  __syncthreads();
  if (t < 64) {
    float tot = 0.f;
#pragma unroll
    for (int r = 0; r < 32; ++r) tot += red[r][t];
    atomicAdd(&sumsq[2048 + bh * 64 + t], tot);
  }
  float* gp = G + (size_t)bh * 4096;
#pragma unroll
  for (int dt = 0; dt < 4; ++dt)
#pragma unroll
    for (int r = 0; r < 4; ++r)
      atomicAdd(&gp[(dt * 16 + g * 4 + r) * 64 + w * 16 + l15], accg[dt][r]);
  float* rp = raw + ((size_t)bh * 2 + comp) * (64 * 256);
#pragma unroll
  for (int dt = 0; dt < 4; ++dt)
#pragma unroll
    for (int kt = 0; kt < 8; ++kt)
#pragma unroll
      for (int r = 0; r < 4; ++r)
        atomicAdd(&rp[(dt * 16 + g * 4 + r) * 256 + (kh * 8 + kt) * 16 + l15],
                  acc[dt][kt][r]);
}

// ---------------- K4: merged epilogue: norms + CA softmax (bf16 out) + projfin ----------------
__global__ __launch_bounds__(256) void k_epi(
    const float* __restrict__ sumsq, const float* __restrict__ G,
    const float* __restrict__ raw, const float* __restrict__ tca,
    const float* __restrict__ tsa, __hip_bfloat16* __restrict__ Gb,
    __hip_bfloat16* __restrict__ kpT, __hip_bfloat16* __restrict__ vpT) {
  __shared__ float iqs[64], iks[64];
  __shared__ float tile[64][65];
  const int bh = blockIdx.x, h = bh & 7;
  const int t = threadIdx.x;
  if (t < 64) {
    iqs[t] = rsqrtf(fmaxf(sumsq[bh * 64 + t], 1e-6f));
    iks[t] = rsqrtf(fmaxf(sumsq[2048 + bh * 64 + t], 1e-6f));
  }
  __syncthreads();
  if (t < 64) {
    const float* row = G + (size_t)bh * 4096 + t * 64;
    const float s0 = iqs[t] * tca[h];
    float vals[64];
    float m = -3.0e38f;
#pragma unroll
    for (int e = 0; e < 64; ++e) {
      float v = row[e] * s0 * iks[e];
      vals[e] = v;
      m = fmaxf(m, v);
    }
    float s = 0.f;
#pragma unroll
    for (int e = 0; e < 64; ++e) { vals[e] = __expf(vals[e] - m); s += vals[e]; }
    float r = 1.0f / s;
#pragma unroll
    for (int e = 0; e < 64; ++e)
      Gb[(size_t)bh * 4096 + t * 64 + e] = __float2bfloat16(vals[e] * r);
  }
  const float ts = tsa[h];
  const float* r0 = raw + (size_t)bh * 2 * 16384;
  for (int kc = 0; kc < 4; ++kc) {
    __syncthreads();
    for (int i = t; i < 4096; i += 256) {
      int d = i >> 6, kk = i & 63;
      tile[d][kk] = r0[d * 256 + kc * 64 + kk];
    }
    __syncthreads();
    for (int i = t; i < 4096; i += 256) {
      int kk = i >> 6, d = i & 63;
      float sc = iqs[d] * iks[d] * ts;
      kpT[(size_t)bh * 16384 + (kc * 64 + kk) * 64 + d] = __float2bfloat16(tile[d][kk] * sc);
    }
  }
  const float* r1 = r0 + 16384;
  for (int i = t; i < 16384; i += 256)
    vpT[(size_t)bh * 16384 + i] = __float2bfloat16(r1[i]);
}

// ---------------- K7: fused output = x_ca + x_sa via MFMA ----------------
__global__ __launch_bounds__(256) void k_xout(
    const __hip_bfloat16* __restrict__ QKVV,
    const __hip_bfloat16* __restrict__ Gb,
    const __hip_bfloat16* __restrict__ kpT,
    const __hip_bfloat16* __restrict__ vpT,
    float* __restrict__ out) {
  __shared__ __hip_bfloat16 vs[64][264];
  __shared__ __hip_bfloat16 ps[4][16][264];
  __shared__ __hip_bfloat16 gs[64][72];
  const int bh = blockIdx.y, b = bh >> 3, h = bh & 7;
  const int nblk = blockIdx.x * 512;
  const int t = threadIdx.x, w = t >> 6, lane = t & 63;
  const int l15 = lane & 15, g = lane >> 4;
  for (int i = t; i < 2048; i += 256) {
    int d = i >> 5, k8 = (i & 31) * 8;
    *reinterpret_cast<uint4*>(&vs[d][k8]) =
        *reinterpret_cast<const uint4*>(&vpT[((size_t)bh * 64 + d) * 256 + k8]);
  }
  for (int i = t; i < 512; i += 256) {
    int row = i >> 3, q = i & 7;
    *reinterpret_cast<uint4*>(&gs[row][q * 8]) =
        *reinterpret_cast<const uint4*>(&Gb[(size_t)bh * 4096 + row * 64 + q * 8]);
  }
  bf16x8 kA[2][16];
#pragma unroll
  for (int s = 0; s < 2; ++s)
#pragma unroll
    for (int f = 0; f < 16; ++f)
      kA[s][f] = *reinterpret_cast<const bf16x8*>(
          &kpT[((size_t)bh * 256 + f * 16 + l15) * 64 + s * 32 + g * 8]);
  __syncthreads();
  const __hip_bfloat16* qbase = QKVV + (size_t)b * SEQ * FOURC + h * HDIM;
  const __hip_bfloat16* vbase = qbase + 2 * CH;
  for (int c = w; c < 32; c += 4) {
    const int n0 = nblk + c * 16;
    bf16x8 qf[2], vf[2];
#pragma unroll
    for (int s = 0; s < 2; ++s) {
      qf[s] = *reinterpret_cast<const bf16x8*>(
          &qbase[(size_t)(n0 + l15) * FOURC + s * 32 + g * 8]);
      vf[s] = *reinterpret_cast<const bf16x8*>(
          &vbase[(size_t)(n0 + l15) * FOURC + s * 32 + g * 8]);
    }
    f32x4 o[4] = {};
#pragma unroll
    for (int dt = 0; dt < 4; ++dt) {
      bf16x8 g0 = *reinterpret_cast<const bf16x8*>(&gs[dt * 16 + l15][g * 8]);
      bf16x8 g1 = *reinterpret_cast<const bf16x8*>(&gs[dt * 16 + l15][32 + g * 8]);
      o[dt] = __builtin_amdgcn_mfma_f32_16x16x32_bf16(vf[0], g0, o[dt], 0, 0, 0);
      o[dt] = __builtin_amdgcn_mfma_f32_16x16x32_bf16(vf[1], g1, o[dt], 0, 0, 0);
    }
    f32x4 acc[16] = {};
#pragma unroll
    for (int f = 0; f < 16; ++f) {
      acc[f] = __builtin_amdgcn_mfma_f32_16x16x32_bf16(kA[0][f], qf[0], acc[f], 0, 0, 0);
      acc[f] = __builtin_amdgcn_mfma_f32_16x16x32_bf16(kA[1][f], qf[1], acc[f], 0, 0, 0);
    }
    float m = -3.0e38f;
#pragma unroll
    for (int f = 0; f < 16; ++f)
#pragma unroll
      for (int r = 0; r < 4; ++r) m = fmaxf(m, acc[f][r]);
    m = fmaxf(m, __shfl_xor(m, 16));
    m = fmaxf(m, __shfl_xor(m, 32));
    float sum = 0.f;
#pragma unroll
    for (int f = 0; f < 16; ++f)
#pragma unroll
      for (int r = 0; r < 4; ++r) {
        float e = __expf(acc[f][r] - m);
        acc[f][r] = e; sum += e;
      }
    sum += __shfl_xor(sum, 16);
    sum += __shfl_xor(sum, 32);
    const float rinv = 1.0f / sum;
#pragma unroll
    for (int f = 0; f < 16; ++f) {
      uint2 pw;
      pw.x = packbf2(acc[f][0] * rinv, acc[f][1] * rinv);
      pw.y = packbf2(acc[f][2] * rinv, acc[f][3] * rinv);
      *reinterpret_cast<uint2*>(&ps[w][l15][f * 16 + g * 4]) = pw;
    }
    __builtin_amdgcn_wave_barrier();
#pragma unroll
    for (int s = 0; s < 8; ++s) {
      bf16x8 pa = *reinterpret_cast<const bf16x8*>(&ps[w][l15][s * 32 + g * 8]);
#pragma unroll
      for (int dt = 0; dt < 4; ++dt) {
        bf16x8 vb = *reinterpret_cast<const bf16x8*>(&vs[dt * 16 + l15][s * 32 + g * 8]);
        o[dt] = __builtin_amdgcn_mfma_f32_16x16x32_bf16(pa, vb, o[dt], 0, 0, 0);
      }
    }
#pragma unroll
    for (int dt = 0; dt < 4; ++dt)
#pragma unroll
      for (int r = 0; r < 4; ++r) {
        size_t oo = ((size_t)(b * SEQ + n0 + g * 4 + r)) * CH + h * HDIM + dt * 16 + l15;
        out[oo] = o[dt][r];
      }
    __builtin_amdgcn_wave_barrier();
  }
}

extern "C" void kernel_launch(void* const* d_in, const int* in_sizes, int n_in,
                              void* d_out, int out_size, void* d_ws, size_t ws_size,
                              hipStream_t stream) {
  const float* x   = (const float*)d_in[0];
  const float* w   = (const float*)d_in[1];
  const float* sp  = (const float*)d_in[2];
  const float* tca = (const float*)d_in[3];
  const float* tsa = (const float*)d_in[4];
  float* out = (float*)d_out;
  char* ws = (char*)d_ws;

  __hip_bfloat16* qkvv = (__hip_bfloat16*)ws;                  // 134217728
  __hip_bfloat16* wt   = (__hip_bfloat16*)(ws + 134217728);    // 2097152
  __hip_bfloat16* pt   = (__hip_bfloat16*)(ws + 136314880);    // 4194304
  __hip_bfloat16* xb   = (__hip_bfloat16*)(ws + 140509184);    // 33554432 (dead after gemm)
  __hip_bfloat16* gb   = (__hip_bfloat16*)(ws + 140509184);    // 262144, aliases xb
  __hip_bfloat16* kpT  = (__hip_bfloat16*)(ws + 174063616);    // 1048576
  __hip_bfloat16* vpT  = (__hip_bfloat16*)(ws + 175112192);    // 1048576
  // contiguous zeroed region: G | sumsq | raw
  float* G     = (float*)(ws + 176177152);                     // 524288
  float* sumsq = (float*)(ws + 176701440);                     // 16384
  float* raw   = (float*)(ws + 176717824);                     // 4194304

  hipMemsetAsync(G, 0, 524288 + 16384 + 4194304, stream);

  hipLaunchKernelGGL(k_wt, dim3(64, 16), dim3(256), 0, stream, w, wt);
  hipLaunchKernelGGL(k_pt, dim3(256, 8), dim3(256), 0, stream, sp, pt);
  hipLaunchKernelGGL(k_xbf, dim3(8192), dim3(256), 0, stream, x, xb);
  hipLaunchKernelGGL(k_gemm_mfma, dim3(4096), dim3(256), 0, stream, xb, wt, qkvv);
  hipLaunchKernelGGL(k_qkstats, dim3(8, 32), dim3(256), 0, stream, qkvv, pt, G, sumsq, raw);
  hipLaunchKernelGGL(k_epi, dim3(32), dim3(256), 0, stream, sumsq, G, raw, tca, tsa,
                     gb, kpT, vpT);
  hipLaunchKernelGGL(k_xout, dim3(16, 32), dim3(256), 0, stream, qkvv, gb, kpT, vpT, out);
}